// Round 2
// baseline (5941.757 us; speedup 1.0000x reference)
//
#include <hip/hip_runtime.h>
#include <hip/hip_bf16.h>
#include <math.h>

#define NB 16
#define SS 1024
#define DD 512
#define SP 1040   // S + 16 (edge pad of 8 both sides, covers max dilation 8)
#define HALF_D 256

typedef __hip_bfloat16 bf16;

static __device__ __forceinline__ float b2f(bf16 v){ return __bfloat162float(v); }

static __device__ __forceinline__ float rd(const void* __restrict__ p, long i, int isf){
  return isf ? ((const float*)p)[i] : b2f(((const bf16*)p)[i]);
}

// Interpret first 4096 uint16 of x as bf16; if max|v| > 1e6 the buffer is f32.
__global__ void k_detect(const void* __restrict__ x, int* __restrict__ flag){
  const unsigned short* u = (const unsigned short*)x;
  int t = threadIdx.x;
  float m = 0.f;
  for (int i = t; i < 4096; i += 256){
    unsigned int bits = ((unsigned int)u[i]) << 16;
    float v = fabsf(__uint_as_float(bits));
    if (isnan(v) || isinf(v)) v = 1e30f;
    m = fmaxf(m, v);
  }
  for (int off = 32; off; off >>= 1) m = fmaxf(m, __shfl_down(m, off));
  __shared__ float sh[4];
  if ((t & 63) == 0) sh[t >> 6] = m;
  __syncthreads();
  if (t == 0){
    float mm = fmaxf(fmaxf(sh[0], sh[1]), fmaxf(sh[2], sh[3]));
    flag[0] = (mm > 1e6f) ? 1 : 0;
  }
}

__global__ void k_cvt(const void* __restrict__ s, float* __restrict__ d, long n, const int* __restrict__ fl){
  int isf = fl[0];
  long i = (long)blockIdx.x*256 + threadIdx.x;
  if (i < n) d[i] = rd(s, i, isf);
}

// [O][C][3] -> [3][O][C] (f32)
__global__ void k_repack3(const void* __restrict__ src, float* __restrict__ dst, int O, int C, const int* __restrict__ fl){
  int isf = fl[0];
  long i = (long)blockIdx.x*256 + threadIdx.x;
  long n = (long)O*C*3;
  if (i >= n) return;
  long oc = (long)O*C;
  int t = (int)(i / oc); long r = i - (long)t*oc; int o = (int)(r / C); int c = (int)(r - (long)o*C);
  dst[i] = rd(src, ((long)o*C + c)*3 + t, isf);
}

// wav_w [4][D(d)][D(e)] -> [4][e][d] f32
__global__ void k_repack_wav(const void* __restrict__ src, float* __restrict__ dst, const int* __restrict__ fl){
  int isf = fl[0];
  long i = (long)blockIdx.x*256 + threadIdx.x;
  if (i >= 4L*DD*DD) return;
  int k = (int)(i >> 18); long r = i & ((1<<18)-1); int e = (int)(r >> 9); int d = (int)(r & 511);
  dst[i] = rd(src, ((long)(k*DD + d))*DD + e, isf);
}

// Dirichlet low-pass kernel: g[d] = (1 + 2*sum_{k=1}^{101} cos(2*pi*k*d/1024)) / 1024
__global__ void k_build_g(float* __restrict__ g){
  int d = blockIdx.x*256 + threadIdx.x;
  if (d >= SS) return;
  float s = 1.f;
  for (int k = 1; k < 102; ++k){
    int r = (k*d) & (SS-1);
    s += 2.f * cosf(6.28318530718f * (float)r * (1.f/SS));
  }
  g[d] = s * (1.f/SS);
}

// Cm[t][s] = g[(s - t) & 1023]
__global__ void k_build_cmat(const float* __restrict__ g, float* __restrict__ cm){
  int i = blockIdx.x*256 + threadIdx.x;
  if (i >= SS*SS) return;
  int t = i >> 10, s = i & (SS-1);
  cm[i] = g[(s - t) & (SS-1)];
}

// x [B,S,D] -> xin [B,D,S] f32
__global__ __launch_bounds__(256) void k_transpose_in(const void* __restrict__ x, float* __restrict__ xin, const int* __restrict__ fl){
  int isf = fl[0];
  __shared__ float tl[32][33];
  int b = blockIdx.z, s0 = blockIdx.x*32, d0 = blockIdx.y*32;
  int tx = threadIdx.x & 31, ty = threadIdx.x >> 5;
  for (int i = ty; i < 32; i += 8)
    tl[i][tx] = rd(x, ((long)(b*SS + s0+i))*DD + d0+tx, isf);
  __syncthreads();
  for (int i = ty; i < 32; i += 8)
    xin[((long)(b*DD + d0+i))*SS + s0+tx] = tl[tx][i];
}

// edge pad [B,D,S] -> [B,D,SP]; optional main-sub
__global__ void k_pad(const float* __restrict__ main_, const float* __restrict__ sub_, float* __restrict__ dst){
  long i = (long)blockIdx.x*256 + threadIdx.x;
  if (i >= (long)NB*DD*SP) return;
  int j = (int)(i % SP); long row = i / SP;
  int cl = j - 8; cl = cl < 0 ? 0 : (cl > SS-1 ? SS-1 : cl);
  long si = row*SS + cl;
  float v = main_[si];
  if (sub_) v -= sub_[si];
  dst[i] = v;
}

// C[m,n] (+)= scale[n] * (sum_k A[m,k]*B[k,n] + bias[m]); batched over z
__global__ __launch_bounds__(256) void k_gemm(const float* __restrict__ A, const float* __restrict__ Bm,
    float* __restrict__ C, int M, int N, int K, int lda, int ldb, int ldc,
    long sB, long sC, const float* __restrict__ bias, const float* __restrict__ scale,
    long sScale, int init)
{
  int z = blockIdx.z;
  Bm += (long)z * sB; C += (long)z * sC;
  const float* sc = scale ? scale + (long)z * sScale : nullptr;
  __shared__ float As[16][132];
  __shared__ float Bs[16][68];
  int m0 = blockIdx.x*128, n0 = blockIdx.y*64;
  int tid = threadIdx.x, tx = tid & 15, ty = tid >> 4;
  int am = tid >> 1, ak = (tid & 1)*8;
  int bk = tid >> 4, bn = (tid & 15)*4;
  float acc[8][4] = {};
  for (int k0 = 0; k0 < K; k0 += 16){
    const float* Ap = A + (long)(m0+am)*lda + (k0+ak);
    #pragma unroll
    for (int i = 0; i < 8; i++) As[ak+i][am] = Ap[i];
    const float* Bp = Bm + (long)(k0+bk)*ldb + (n0+bn);
    #pragma unroll
    for (int i = 0; i < 4; i++) Bs[bk][bn+i] = Bp[i];
    __syncthreads();
    #pragma unroll
    for (int kk = 0; kk < 16; kk++){
      float a[8], bv[4];
      #pragma unroll
      for (int i = 0; i < 8; i++) a[i] = As[kk][ty*8+i];
      #pragma unroll
      for (int j = 0; j < 4; j++) bv[j] = Bs[kk][tx*4+j];
      #pragma unroll
      for (int i = 0; i < 8; i++)
        #pragma unroll
        for (int j = 0; j < 4; j++) acc[i][j] = fmaf(a[i], bv[j], acc[i][j]);
    }
    __syncthreads();
  }
  #pragma unroll
  for (int i = 0; i < 8; i++){
    int m = m0 + ty*8 + i;
    float bb = bias ? bias[m] : 0.f;
    #pragma unroll
    for (int j = 0; j < 4; j++){
      int n = n0 + tx*4 + j;
      float v = acc[i][j] + bb;
      if (sc) v *= sc[n];
      float* cp = C + (long)m*ldc + n;
      *cp = init ? v : (*cp + v);
    }
  }
}

__global__ void k_gelu_bias(float* __restrict__ buf, const float* __restrict__ bias){
  long i = (long)blockIdx.x*256 + threadIdx.x;
  if (i >= (long)NB*DD*SS) return;
  int o = (int)((i >> 10) & (DD-1));
  float v = buf[i] + bias[o];
  buf[i] = 0.5f*v*(1.f + erff(v*0.70710678f));
}

__global__ void k_bnsilu(float* __restrict__ buf, const float* __restrict__ gm, const float* __restrict__ bt){
  long i = (long)blockIdx.x*256 + threadIdx.x;
  if (i >= (long)NB*DD*SS) return;
  int o = (int)((i >> 10) & (DD-1));
  float v = buf[i]*(gm[o]*rsqrtf(1.f + 1e-5f)) + bt[o];
  buf[i] = v/(1.f + expf(-v));
}

__global__ void k_silu(const float* __restrict__ s, float* __restrict__ d, long n){
  long i = (long)blockIdx.x*256 + threadIdx.x;
  if (i >= n) return;
  float v = s[i];
  d[i] = v/(1.f + expf(-v));
}

__global__ __launch_bounds__(256) void k_pool(const float* __restrict__ h2, float* __restrict__ feat){
  int blk = blockIdx.x;
  const float* row = h2 + (long)blk*SS;
  int t = threadIdx.x;
  float s = 0.f;
  for (int i = t; i < SS; i += 256){ float v = row[i]; s += v/(1.f + expf(-v)); }
  for (int off = 32; off; off >>= 1) s += __shfl_down(s, off);
  __shared__ float sh[4];
  if ((t & 63) == 0) sh[t >> 6] = s;
  __syncthreads();
  if (t == 0) feat[blk] = (sh[0]+sh[1]+sh[2]+sh[3]) * (1.f/SS);
}

__global__ void k_params(const float* __restrict__ feat, const float* __restrict__ pw,
                         const float* __restrict__ pb, float* __restrict__ dynA, float* __restrict__ dynB){
  int t = threadIdx.x;
  if (t >= 128) return;
  int b = t >> 3, j = t & 7;
  float s = pb[j];
  for (int c = 0; c < HALF_D; c++) s += feat[b*HALF_D + c]*pw[j*HALF_D + c];
  int k = j >> 1;
  if ((j & 1) == 0){
    float sp = s > 20.f ? s : log1pf(expf(s));
    dynA[b*4 + k] = sp + 0.01f;
  } else {
    dynB[b*4 + k] = 1024.f/(1.f + expf(-s));
  }
}

__global__ void k_psi(const float* __restrict__ dynA, const float* __restrict__ dynB, float* __restrict__ psi){
  int i = blockIdx.x*256 + threadIdx.x;
  if (i >= NB*4*SS) return;
  int b = i >> 12, k = (i >> 10) & 3, s = i & (SS-1);
  float u = ((float)s - dynB[b*4 + k]) / dynA[b*4 + k];
  psi[i] = 0.86732507f*(1.f - u*u)*expf(-0.5f*u*u);
}

__global__ __launch_bounds__(256) void k_y(const float* __restrict__ base, const float* __restrict__ kan,
    const float* __restrict__ gate, const void* __restrict__ x, float* __restrict__ y, const int* __restrict__ fl){
  int isf = fl[0];
  __shared__ float tl[32][33];
  int b = blockIdx.z, s0 = blockIdx.x*32, d0 = blockIdx.y*32;
  int tx = threadIdx.x & 31, ty = threadIdx.x >> 5;
  for (int i = ty; i < 32; i += 8){
    long idx = ((long)(b*DD + d0+i))*SS + s0+tx;
    float bs = base[idx], kn = kan[idx], gt = gate[idx];
    tl[i][tx] = bs + kn * (2.f/(1.f + expf(-gt)));
  }
  __syncthreads();
  for (int i = ty; i < 32; i += 8){
    long o = ((long)(b*SS + s0+i))*DD + d0+tx;
    y[o] = tl[tx][i] + rd(x, o, isf);
  }
}

__global__ __launch_bounds__(128) void k_ln(const float* __restrict__ y, const float* __restrict__ gm,
    const float* __restrict__ bt, void* __restrict__ out, const int* __restrict__ fl){
  int isf = fl[0];
  int bs = blockIdx.x;
  const float* row = y + (long)bs*DD;
  int t = threadIdx.x;
  float4 v = ((const float4*)row)[t];
  float s  = v.x + v.y + v.z + v.w;
  float ss = v.x*v.x + v.y*v.y + v.z*v.z + v.w*v.w;
  for (int off = 32; off; off >>= 1){ s += __shfl_down(s, off); ss += __shfl_down(ss, off); }
  __shared__ float sh[4];
  if ((t & 63) == 0){ sh[t >> 6] = s; sh[2 + (t >> 6)] = ss; }
  __syncthreads();
  float S1 = sh[0] + sh[1], S2 = sh[2] + sh[3];
  float mean = S1*(1.f/DD), var = S2*(1.f/DD) - mean*mean;
  float rstd = rsqrtf(var + 1e-5f);
  float vv[4] = {v.x, v.y, v.z, v.w};
  #pragma unroll
  for (int j = 0; j < 4; j++){
    int d = t*4 + j;
    float val = (vv[j] - mean)*rstd*gm[d] + bt[d];
    if (isf) ((float*)out)[(long)bs*DD + d] = val;
    else     ((bf16*)out)[(long)bs*DD + d] = __float2bfloat16(val);
  }
}

static inline void gemm_launch(hipStream_t st, const float* A, const float* B, float* C,
  int M, int N, int K, int lda, int ldb, int ldc, long sB, long sC, int batch,
  const float* bias, const float* scale, long sScale, int init)
{
  dim3 g(M/128, N/64, batch);
  k_gemm<<<g, dim3(256), 0, st>>>(A, B, C, M, N, K, lda, ldb, ldc, sB, sC, bias, scale, sScale, init);
}

extern "C" void kernel_launch(void* const* d_in, const int* in_sizes, int n_in,
                              void* d_out, int out_size, void* d_ws, size_t ws_size,
                              hipStream_t stream){
  const void* x       = d_in[0];
  const void* conv_w  = d_in[1];
  const void* conv_b  = d_in[2];
  const void* fusion_w= d_in[3];
  const void* fusion_b= d_in[4];
  const void* refine_w= d_in[5];
  const void* refine_b= d_in[6];
  const void* hyp1_w  = d_in[7];
  const void* hyp1_b  = d_in[8];
  const void* bn_g    = d_in[9];
  const void* bn_b    = d_in[10];
  const void* hyp2_w  = d_in[11];
  const void* hyp2_b  = d_in[12];
  const void* proj_w  = d_in[13];
  const void* proj_b  = d_in[14];
  const void* gate_w  = d_in[15];
  const void* gate_b  = d_in[16];
  const void* base_w  = d_in[17];
  const void* base_b  = d_in[18];
  const void* wav_w   = d_in[19];
  const void* wav_b   = d_in[20];
  const void* ln_g    = d_in[21];
  const void* ln_b    = d_in[22];
  float* ws = (float*)d_ws;

  const long SZ  = (long)NB*DD*SS;
  const long SZP = (long)NB*DD*SP;

  float* bufA = ws;
  float* bufB = ws + SZ;
  float* bufC = ws + 2*SZ;
  float* bufT = ws + 3*SZ;
  float* bufE = ws + 4*SZ;
  float* bufP = ws + 5*SZ;
  float* W    = ws + 5*SZ + SZP;
  float* Wc   = W;                      // [3][4*512][512]
  float* Wr   = Wc  + 4L*3*DD*DD;
  float* Wh1  = Wr  + 3L*DD*DD;
  float* Wh2  = Wh1 + 3L*DD*DD;
  float* WwT  = Wh2 + 3L*HALF_D*DD;
  float* Fw   = WwT + 4L*DD*DD;
  float* BW   = Fw  + (long)DD*4*DD;
  float* GW   = BW  + (long)DD*DD;
  float* Cm   = GW  + (long)DD*DD;
  float* g    = Cm  + (long)SS*SS;
  float* feat = g   + SS;
  float* dynA = feat + NB*HALF_D;
  float* dynB = dynA + 64;
  float* psi  = dynB + 64;
  float* fz_b = psi  + (long)NB*4*SS;
  float* rf_b = fz_b + DD;
  float* h1_b = rf_b + DD;
  float* h2_b = h1_b + DD;
  float* bs_b = h2_b + HALF_D;
  float* gt_b = bs_b + DD;
  float* wv_b = gt_b + DD;
  float* cb_f = wv_b + 4*DD;
  float* bng_f= cb_f + 4*DD;
  float* bnb_f= bng_f + DD;
  float* pw_f = bnb_f + DD;
  float* pb_f = pw_f + 8*HALF_D;
  float* lng_f= pb_f + 16;
  float* lnb_f= lng_f + DD;
  int*   flag = (int*)(lnb_f + DD);
  const long NEED = ((float*)flag + 16) - ws;
  if (ws_size < (size_t)NEED * 4) return;

  auto g1 = [](long n){ return dim3((unsigned)((n + 255)/256)); };

  k_detect<<<1, 256, 0, stream>>>(x, flag);

  k_transpose_in<<<dim3(SS/32, DD/32, NB), 256, 0, stream>>>(x, bufA, flag);
  // conv_w [4*512][512][3] -> Wc [3][4*512][512]; A(i,t) = Wc + t*4*DD*DD + i*DD*DD
  k_repack3<<<g1(12L*DD*DD), 256, 0, stream>>>(conv_w, Wc, 4*DD, DD, flag);
  k_repack3<<<g1(3L*DD*DD), 256, 0, stream>>>(refine_w, Wr, DD, DD, flag);
  k_repack3<<<g1(3L*DD*DD), 256, 0, stream>>>(hyp1_w, Wh1, DD, DD, flag);
  k_repack3<<<g1(3L*HALF_D*DD), 256, 0, stream>>>(hyp2_w, Wh2, HALF_D, DD, flag);
  k_repack_wav<<<g1(4L*DD*DD), 256, 0, stream>>>(wav_w, WwT, flag);
  k_cvt<<<g1((long)DD*4*DD), 256, 0, stream>>>(fusion_w, Fw, (long)DD*4*DD, flag);
  k_cvt<<<g1((long)DD*DD), 256, 0, stream>>>(base_w, BW, (long)DD*DD, flag);
  k_cvt<<<g1((long)DD*DD), 256, 0, stream>>>(gate_w, GW, (long)DD*DD, flag);
  k_cvt<<<g1(DD), 256, 0, stream>>>(fusion_b, fz_b, DD, flag);
  k_cvt<<<g1(DD), 256, 0, stream>>>(refine_b, rf_b, DD, flag);
  k_cvt<<<g1(DD), 256, 0, stream>>>(hyp1_b, h1_b, DD, flag);
  k_cvt<<<g1(HALF_D), 256, 0, stream>>>(hyp2_b, h2_b, HALF_D, flag);
  k_cvt<<<g1(DD), 256, 0, stream>>>(base_b, bs_b, DD, flag);
  k_cvt<<<g1(DD), 256, 0, stream>>>(gate_b, gt_b, DD, flag);
  k_cvt<<<g1(4*DD), 256, 0, stream>>>(wav_b, wv_b, 4*DD, flag);
  k_cvt<<<g1(4*DD), 256, 0, stream>>>(conv_b, cb_f, 4*DD, flag);
  k_cvt<<<g1(DD), 256, 0, stream>>>(bn_g, bng_f, DD, flag);
  k_cvt<<<g1(DD), 256, 0, stream>>>(bn_b, bnb_f, DD, flag);
  k_cvt<<<g1(8*HALF_D), 256, 0, stream>>>(proj_w, pw_f, 8*HALF_D, flag);
  k_cvt<<<g1(8), 256, 0, stream>>>(proj_b, pb_f, 8, flag);
  k_cvt<<<g1(DD), 256, 0, stream>>>(ln_g, lng_f, DD, flag);
  k_cvt<<<g1(DD), 256, 0, stream>>>(ln_b, lnb_f, DD, flag);
  k_build_g<<<g1(SS), 256, 0, stream>>>(g);
  k_build_cmat<<<g1((long)SS*SS), 256, 0, stream>>>(g, Cm);

  gemm_launch(stream, bufA, Cm, bufB, NB*DD, SS, SS, SS, SS, SS, 0, 0, 1,
              nullptr, nullptr, 0, 1);

  const int DIL[4] = {1, 2, 4, 8};
  float* cur = bufB; float* nxt = bufC;
  for (int it = 0; it < 2; ++it){
    k_pad<<<g1(SZP), 256, 0, stream>>>(cur, nullptr, bufP);
    for (int i = 0; i < 4; i++){
      for (int t = 0; t < 3; t++)
        gemm_launch(stream, Wc + (long)t*(4L*DD*DD) + (long)i*DD*DD, bufP + 8 + (t-1)*DIL[i], bufT,
                    DD, SS, DD, DD, SP, SS, (long)DD*SP, (long)DD*SS, NB,
                    nullptr, nullptr, 0, t == 0);
      k_gelu_bias<<<g1(SZ), 256, 0, stream>>>(bufT, cb_f + (long)i*DD);
      gemm_launch(stream, Fw + (long)i*DD, bufT, nxt,
                  DD, SS, DD, 4*DD, SS, SS, (long)DD*SS, (long)DD*SS, NB,
                  (i == 0) ? fz_b : nullptr, nullptr, 0, i == 0);
    }
    float* tmp = cur; cur = nxt; nxt = tmp;
  }

  k_pad<<<g1(SZP), 256, 0, stream>>>(bufA, cur, bufP);
  for (int t = 0; t < 3; t++)
    gemm_launch(stream, Wr + (long)t*DD*DD, bufP + 8 + (t-1), bufE,
                DD, SS, DD, DD, SP, SS, (long)DD*SP, (long)DD*SS, NB,
                (t == 0) ? rf_b : nullptr, nullptr, 0, t == 0);

  k_pad<<<g1(SZP), 256, 0, stream>>>(cur, nullptr, bufP);
  for (int t = 0; t < 3; t++)
    gemm_launch(stream, Wh1 + (long)t*DD*DD, bufP + 8 + (t-1), bufT,
                DD, SS, DD, DD, SP, SS, (long)DD*SP, (long)DD*SS, NB,
                (t == 0) ? h1_b : nullptr, nullptr, 0, t == 0);
  k_bnsilu<<<g1(SZ), 256, 0, stream>>>(bufT, bng_f, bnb_f);
  k_pad<<<g1(SZP), 256, 0, stream>>>(bufT, nullptr, bufP);
  for (int t = 0; t < 3; t++)
    gemm_launch(stream, Wh2 + (long)t*HALF_D*DD, bufP + 8 + (t-1), bufC,
                HALF_D, SS, DD, DD, SP, SS, (long)DD*SP, (long)HALF_D*SS, NB,
                (t == 0) ? h2_b : nullptr, nullptr, 0, t == 0);
  k_pool<<<NB*HALF_D, 256, 0, stream>>>(bufC, feat);
  k_params<<<1, 128, 0, stream>>>(feat, pw_f, pb_f, dynA, dynB);
  k_psi<<<g1(NB*4*SS), 256, 0, stream>>>(dynA, dynB, psi);

  k_silu<<<g1(SZ), 256, 0, stream>>>(cur, bufA, SZ);
  gemm_launch(stream, BW, bufA, bufC, DD, SS, DD, DD, SS, SS,
              (long)DD*SS, (long)DD*SS, NB, bs_b, nullptr, 0, 1);
  gemm_launch(stream, GW, bufC, bufT, DD, SS, DD, DD, SS, SS,
              (long)DD*SS, (long)DD*SS, NB, gt_b, nullptr, 0, 1);
  for (int k = 0; k < 4; k++)
    gemm_launch(stream, WwT + (long)k*DD*DD, bufE, bufB, DD, SS, DD, DD, SS, SS,
                (long)DD*SS, (long)DD*SS, NB,
                wv_b + k*DD, psi + (long)k*SS, (long)4*SS, k == 0);

  k_y<<<dim3(SS/32, DD/32, NB), 256, 0, stream>>>(bufC, bufB, bufT, x, bufE, flag);
  k_ln<<<NB*SS, 128, 0, stream>>>(bufE, lng_f, lnb_f, d_out, flag);
}

// Round 3
// 912.843 us; speedup vs baseline: 6.5091x; 6.5091x over previous
//
#include <hip/hip_runtime.h>
#include <hip/hip_bf16.h>
#include <math.h>

#define NB 16
#define SS 1024
#define DD 512
#define SP 1040   // S + 16 (edge pad of 8 both sides, covers max dilation 8)
#define HD 256

typedef unsigned short US;
typedef short bf16x8 __attribute__((ext_vector_type(8)));
typedef float f32x4 __attribute__((ext_vector_type(4)));
typedef __attribute__((address_space(1))) const void gv1;
typedef __attribute__((address_space(3))) void lv3;

static __device__ __forceinline__ float b2sf(US u){ return __uint_as_float(((unsigned)u)<<16); }
static __device__ __forceinline__ US f2b(float f){
  __hip_bfloat16 h = __float2bfloat16(f);
  union { __hip_bfloat16 h; US u; } c; c.h = h; return c.u;
}
static __device__ __forceinline__ float rd(const void* __restrict__ p, long i, int isf){
  return isf ? ((const float*)p)[i] : b2sf(((const US*)p)[i]);
}

// ---------------- dtype detection ----------------
__global__ void k_detect(const void* __restrict__ x, int* __restrict__ flag){
  const US* u = (const US*)x;
  int t = threadIdx.x;
  float m = 0.f;
  for (int i = t; i < 4096; i += 256){
    float v = fabsf(b2sf(u[i]));
    if (isnan(v) || isinf(v)) v = 1e30f;
    m = fmaxf(m, v);
  }
  for (int off = 32; off; off >>= 1) m = fmaxf(m, __shfl_down(m, off));
  __shared__ float sh[4];
  if ((t & 63) == 0) sh[t >> 6] = m;
  __syncthreads();
  if (t == 0){
    float mm = fmaxf(fmaxf(sh[0], sh[1]), fmaxf(sh[2], sh[3]));
    flag[0] = (mm > 1e6f) ? 1 : 0;
  }
}

// ---------------- converts / repacks ----------------
__global__ void k_cvt_f(const void* __restrict__ s, float* __restrict__ d, long n, const int* __restrict__ fl){
  int isf = fl[0];
  long i = (long)blockIdx.x*256 + threadIdx.x;
  if (i < n) d[i] = rd(s, i, isf);
}
__global__ void k_cvt_b(const void* __restrict__ s, US* __restrict__ d, long n, const int* __restrict__ fl){
  int isf = fl[0];
  long i = (long)blockIdx.x*256 + threadIdx.x;
  if (i < n) d[i] = f2b(rd(s, i, isf));
}
// src [O][C][3] -> dst [O][3*C] bf16 : dst[o][t*C+c] = src[o][c][t]
__global__ void k_repack3(const void* __restrict__ src, US* __restrict__ dst, int O, int C, const int* __restrict__ fl){
  int isf = fl[0];
  long i = (long)blockIdx.x*256 + threadIdx.x;
  long n = (long)O*3*C;
  if (i >= n) return;
  int o = (int)(i / (3*C)); int r = (int)(i - (long)o*3*C); int t = r / C; int c = r - t*C;
  dst[i] = f2b(rd(src, ((long)o*C + c)*3 + t, isf));
}
// wav_w [4][d][e] -> [4][e][d] bf16
__global__ void k_repack_wav(const void* __restrict__ src, US* __restrict__ dst, const int* __restrict__ fl){
  int isf = fl[0];
  long i = (long)blockIdx.x*256 + threadIdx.x;
  if (i >= 4L*DD*DD) return;
  int k = (int)(i >> 18); long r = i & ((1<<18)-1); int e = (int)(r >> 9); int d = (int)(r & 511);
  dst[i] = f2b(rd(src, ((long)(k*DD + d))*DD + e, isf));
}
// Dirichlet low-pass kernel
__global__ void k_build_g(float* __restrict__ g){
  int d = blockIdx.x*256 + threadIdx.x;
  if (d >= SS) return;
  float s = 1.f;
  for (int k = 1; k < 102; ++k){
    int r = (k*d) & (SS-1);
    s += 2.f * cosf(6.28318530718f * (float)r * (1.f/SS));
  }
  g[d] = s * (1.f/SS);
}
__global__ void k_build_cmat(const float* __restrict__ g, US* __restrict__ cm){
  int i = blockIdx.x*256 + threadIdx.x;
  if (i >= SS*SS) return;
  int t = i >> 10, s = i & (SS-1);
  cm[i] = f2b(g[(s - t) & (SS-1)]);
}
// x [B,S,D] -> xT [B,D,S] bf16
__global__ __launch_bounds__(256) void k_transpose_b(const void* __restrict__ x, US* __restrict__ xt, const int* __restrict__ fl){
  int isf = fl[0];
  __shared__ float tl[32][33];
  int b = blockIdx.z, s0 = blockIdx.x*32, d0 = blockIdx.y*32;
  int tx = threadIdx.x & 31, ty = threadIdx.x >> 5;
  for (int i = ty; i < 32; i += 8)
    tl[i][tx] = rd(x, ((long)(b*SS + s0+i))*DD + d0+tx, isf);
  __syncthreads();
  for (int i = ty; i < 32; i += 8)
    xt[((long)(b*DD + d0+i))*SS + s0+tx] = f2b(tl[tx][i]);
}
// edge pad rows: dst[b][j][d] = src[b][clamp(j-8)][d]  (or x - src when xsub)
__global__ void k_pad_b(const US* __restrict__ src, const void* __restrict__ xsub, US* __restrict__ dst, const int* __restrict__ fl){
  long i = (long)blockIdx.x*256 + threadIdx.x;   // 4-elem chunks
  const long TOT = (long)NB*SP*128;
  if (i >= TOT) return;
  int c4 = (int)(i & 127);
  int j  = (int)((i >> 7) % SP);
  int b  = (int)(i / (128L*SP));
  int sr = j - 8; sr = sr < 0 ? 0 : (sr > SS-1 ? SS-1 : sr);
  long si = ((long)(b*SS + sr))*DD + c4*4;
  ushort4 sv = *(const ushort4*)&src[si];
  float v0=b2sf(sv.x), v1=b2sf(sv.y), v2=b2sf(sv.z), v3=b2sf(sv.w);
  if (xsub){
    if (fl[0]){
      float4 xv = *(const float4*)((const float*)xsub + si);
      v0 = xv.x - v0; v1 = xv.y - v1; v2 = xv.z - v2; v3 = xv.w - v3;
    } else {
      ushort4 xv = *(const ushort4*)((const US*)xsub + si);
      v0 = b2sf(xv.x) - v0; v1 = b2sf(xv.y) - v1; v2 = b2sf(xv.z) - v2; v3 = b2sf(xv.w) - v3;
    }
  }
  ushort4 o; o.x=f2b(v0); o.y=f2b(v1); o.z=f2b(v2); o.w=f2b(v3);
  *(ushort4*)&dst[((long)(b*SP + j))*DD + c4*4] = o;
}
__global__ void k_silu_b(const US* __restrict__ s, US* __restrict__ d){
  long i = (long)blockIdx.x*256 + threadIdx.x;
  if (i >= (long)NB*SS*DD/4) return;
  ushort4 sv = *(const ushort4*)&s[i*4];
  float v[4] = {b2sf(sv.x), b2sf(sv.y), b2sf(sv.z), b2sf(sv.w)};
  ushort4 o;
  US* op = (US*)&o;
  #pragma unroll
  for (int r = 0; r < 4; r++){ float t = v[r]; op[r] = f2b(t/(1.f + expf(-t))); }
  *(ushort4*)&d[i*4] = o;
}

// ---------------- MFMA GEMM ----------------
// C[m][n] = sum_k A[m][k] * Bt[n][k], batched over z.
// A: bf16 [M][K] row-major (k contiguous). Bt rows indexed by n (+srowOff for taps), ldbB bytes/row.
// EPI: 0=bias+store bf16 T-layout out[b][n][moff+m]; 1=+gelu; 2=+bn+silu; 3=+silu;
//      4=wav: out_f32[b][n][m] (+)= scale[n]*(acc+bias[m]); 5=NT store bf16 out[b][m][n], no bias.
template<int EPI, bool TAPPED>
__global__ __launch_bounds__(256) void k_mfma(
    const US* __restrict__ A, const US* __restrict__ Bact, void* __restrict__ Out,
    int M, int K, long sBbytes, int ldbB, int dil,
    long sOut, int ldo, int moff,
    const float* __restrict__ bias, const float* __restrict__ s1v, const float* __restrict__ s2v,
    const float* __restrict__ scale, long sScale, int init)
{
  __shared__ alignas(16) US As[128*64];
  __shared__ alignas(16) US Bs[128*64];
  const int m0 = blockIdx.x*128, n0 = blockIdx.y*128, b = blockIdx.z;
  const char* Bb = (const char*)Bact + (long)b*sBbytes;
  const int tid = threadIdx.x;
  const int lane = tid & 63, w = tid >> 6;
  const int wr = w >> 1, wc = w & 1;
  const int col = lane & 15, g = lane >> 4;

  f32x4 acc[4][4] = {};

  int rows_[4], sls_[4];
  #pragma unroll
  for (int i = 0; i < 4; i++){
    int c = w*256 + i*64 + lane;
    rows_[i] = c >> 3;
    sls_[i] = (c & 7) ^ ((c >> 3) & 7);
  }

  for (int k0 = 0; k0 < K; k0 += 64){
    const int c0 = TAPPED ? (k0 & 511) : k0;
    const int srowOff = TAPPED ? (8 + ((k0 >> 9) - 1)*dil) : 0;
    __syncthreads();   // previous iter's LDS reads done
    #pragma unroll
    for (int i = 0; i < 4; i++){
      const char* ga = (const char*)A + ((long)(m0 + rows_[i])*K + k0)*2 + sls_[i]*16;
      __builtin_amdgcn_global_load_lds((gv1*)ga, (lv3*)&As[(w*256 + i*64)*8], 16, 0, 0);
      const char* gb = Bb + (long)(n0 + rows_[i] + srowOff)*ldbB + c0*2 + sls_[i]*16;
      __builtin_amdgcn_global_load_lds((gv1*)gb, (lv3*)&Bs[(w*256 + i*64)*8], 16, 0, 0);
    }
    __syncthreads();   // vmcnt(0) drained by compiler before barrier
    #pragma unroll
    for (int kk = 0; kk < 2; kk++){
      bf16x8 af[4], bf[4];
      #pragma unroll
      for (int f = 0; f < 4; f++){
        int rowa = wr*64 + f*16 + col;
        int sla = (g + kk*4) ^ (rowa & 7);
        af[f] = *(const bf16x8*)&As[rowa*64 + sla*8];
        int rowb = wc*64 + f*16 + col;
        int slb = (g + kk*4) ^ (rowb & 7);
        bf[f] = *(const bf16x8*)&Bs[rowb*64 + slb*8];
      }
      #pragma unroll
      for (int fm = 0; fm < 4; fm++)
        #pragma unroll
        for (int fn = 0; fn < 4; fn++)
          acc[fm][fn] = __builtin_amdgcn_mfma_f32_16x16x32_bf16(af[fm], bf[fn], acc[fm][fn], 0, 0, 0);
    }
  }

  // epilogue
  #pragma unroll
  for (int fm = 0; fm < 4; fm++){
    const int mm = m0 + wr*64 + fm*16 + g*4;   // 4 consecutive m per lane (reg r)
    #pragma unroll
    for (int fn = 0; fn < 4; fn++){
      const int nn = n0 + wc*64 + fn*16 + col;
      f32x4 v = acc[fm][fn];
      if (EPI == 5){
        US* o = (US*)Out + (long)b*sOut + (long)mm*ldo + nn;
        #pragma unroll
        for (int r = 0; r < 4; r++) o[(long)r*ldo] = f2b(v[r]);
      } else if (EPI == 4){
        float sc = scale[(long)b*sScale + nn];
        float* o = (float*)Out + (long)b*sOut + (long)nn*ldo + mm;
        f32x4 nv;
        #pragma unroll
        for (int r = 0; r < 4; r++) nv[r] = sc * (v[r] + bias[mm + r]);
        if (init) *(f32x4*)o = nv;
        else { f32x4 ov = *(f32x4*)o; *(f32x4*)o = ov + nv; }
      } else {
        US pk[4];
        #pragma unroll
        for (int r = 0; r < 4; r++){
          int m = mm + r;
          float val = v[r] + bias[m];
          if (EPI == 1) val = 0.5f*val*(1.f + erff(val*0.70710678f));
          if (EPI == 2){ val = val*(s1v[m]*0.99999500f) + s2v[m]; val = val/(1.f + expf(-val)); }
          if (EPI == 3){ val = val/(1.f + expf(-val)); }
          pk[r] = f2b(val);
        }
        US* o = (US*)Out + (long)b*sOut + (long)nn*ldo + moff + mm;
        *(ushort4*)o = *(ushort4*)pk;
      }
    }
  }
}

// ---------------- small tail kernels ----------------
__global__ __launch_bounds__(256) void k_pool(const US* __restrict__ h2, float* __restrict__ feat){
  int b = blockIdx.x, c = threadIdx.x;
  float s = 0.f;
  for (int t = 0; t < SS; t++) s += b2sf(h2[((long)(b*SS + t))*HD + c]);
  feat[b*HD + c] = s * (1.f/SS);
}
__global__ void k_params(const float* __restrict__ feat, const float* __restrict__ pw,
                         const float* __restrict__ pb, float* __restrict__ dynA, float* __restrict__ dynB){
  int t = threadIdx.x;
  if (t >= 128) return;
  int b = t >> 3, j = t & 7;
  float s = pb[j];
  for (int c = 0; c < HD; c++) s += feat[b*HD + c]*pw[j*HD + c];
  int k = j >> 1;
  if ((j & 1) == 0){
    float sp = s > 20.f ? s : log1pf(expf(s));
    dynA[b*4 + k] = sp + 0.01f;
  } else {
    dynB[b*4 + k] = 1024.f/(1.f + expf(-s));
  }
}
__global__ void k_psi(const float* __restrict__ dynA, const float* __restrict__ dynB, float* __restrict__ psi){
  int i = blockIdx.x*256 + threadIdx.x;
  if (i >= NB*4*SS) return;
  int b = i >> 12, k = (i >> 10) & 3, s = i & (SS-1);
  float u = ((float)s - dynB[b*4 + k]) / dynA[b*4 + k];
  psi[i] = 0.86732507f*(1.f - u*u)*expf(-0.5f*u*u);
}
// y = base + kan*2*sigmoid(gate) + x; LayerNorm over D; store out (dual dtype)
__global__ __launch_bounds__(128) void k_final(const US* __restrict__ base, const float* __restrict__ kan,
    const US* __restrict__ gate, const void* __restrict__ x, void* __restrict__ out,
    const float* __restrict__ lng, const float* __restrict__ lnb, const int* __restrict__ fl){
  int isf = fl[0];
  long row = blockIdx.x;               // b*S + s
  int t = threadIdx.x;
  long off = row*DD + t*4;
  ushort4 bs = *(const ushort4*)&base[off];
  float4  kn = *(const float4*)&kan[off];
  ushort4 gt = *(const ushort4*)&gate[off];
  float xv[4];
  if (isf){ float4 q = *(const float4*)((const float*)x + off); xv[0]=q.x; xv[1]=q.y; xv[2]=q.z; xv[3]=q.w; }
  else { ushort4 q = *(const ushort4*)((const US*)x + off); xv[0]=b2sf(q.x); xv[1]=b2sf(q.y); xv[2]=b2sf(q.z); xv[3]=b2sf(q.w); }
  float bv[4] = {b2sf(bs.x), b2sf(bs.y), b2sf(bs.z), b2sf(bs.w)};
  float gv[4] = {b2sf(gt.x), b2sf(gt.y), b2sf(gt.z), b2sf(gt.w)};
  float kv[4] = {kn.x, kn.y, kn.z, kn.w};
  float y[4];
  float s = 0.f, ss = 0.f;
  #pragma unroll
  for (int r = 0; r < 4; r++){
    float amp = 2.f/(1.f + expf(-gv[r]));
    y[r] = bv[r] + kv[r]*amp + xv[r];
    s += y[r]; ss += y[r]*y[r];
  }
  for (int o = 32; o; o >>= 1){ s += __shfl_down(s, o); ss += __shfl_down(ss, o); }
  __shared__ float sh[4];
  int lane = t & 63, wid = t >> 6;
  if (lane == 0){ sh[wid*2] = s; sh[wid*2+1] = ss; }
  __syncthreads();
  float S1 = sh[0] + sh[2], S2 = sh[1] + sh[3];
  float mean = S1*(1.f/DD), var = S2*(1.f/DD) - mean*mean;
  float rstd = rsqrtf(var + 1e-5f);
  #pragma unroll
  for (int r = 0; r < 4; r++){
    int d = t*4 + r;
    float val = (y[r] - mean)*rstd*lng[d] + lnb[d];
    if (isf) ((float*)out)[off + r] = val;
    else     ((US*)out)[off + r] = f2b(val);
  }
}

extern "C" void kernel_launch(void* const* d_in, const int* in_sizes, int n_in,
                              void* d_out, int out_size, void* d_ws, size_t ws_size,
                              hipStream_t stream){
  const void* x       = d_in[0];
  const void* conv_w  = d_in[1];
  const void* conv_b  = d_in[2];
  const void* fusion_w= d_in[3];
  const void* fusion_b= d_in[4];
  const void* refine_w= d_in[5];
  const void* refine_b= d_in[6];
  const void* hyp1_w  = d_in[7];
  const void* hyp1_b  = d_in[8];
  const void* bn_g    = d_in[9];
  const void* bn_b    = d_in[10];
  const void* hyp2_w  = d_in[11];
  const void* hyp2_b  = d_in[12];
  const void* proj_w  = d_in[13];
  const void* proj_b  = d_in[14];
  const void* gate_w  = d_in[15];
  const void* gate_b  = d_in[16];
  const void* base_w  = d_in[17];
  const void* base_b  = d_in[18];
  const void* wav_w   = d_in[19];
  const void* wav_b   = d_in[20];
  const void* ln_g    = d_in[21];
  const void* ln_b    = d_in[22];

  char* wsb = (char*)d_ws;
  long off = 0;
  auto AA = [&](long bytes)->char*{ char* p = wsb + off; off += (bytes + 255) & ~255L; return p; };
  US* padG  = (US*)AA((long)NB*SP*DD*2);   // pad buffer, later gate
  US* smA   = (US*)AA((long)NB*SS*DD*2);   // x_smooth ping
  US* smB   = (US*)AA((long)NB*SS*DD*2);   // x_smooth pong / spike
  US* xTh   = (US*)AA((long)NB*SS*DD*2);   // xT, later h1
  US* cc    = (US*)AA((long)NB*SS*2048*2); // concat, later h2+siluS
  US* baseB = (US*)AA((long)NB*SS*DD*2);
  float* kan = (float*)AA((long)NB*SS*DD*4);
  US* Wc  = (US*)AA(4L*512*1536*2);
  US* Wr  = (US*)AA(512L*1536*2);
  US* Wh1 = (US*)AA(512L*1536*2);
  US* Wh2 = (US*)AA(256L*1536*2);
  US* Wwv = (US*)AA(4L*512*512*2);
  US* Fw  = (US*)AA(512L*2048*2);
  US* BW  = (US*)AA(512L*512*2);
  US* GW  = (US*)AA(512L*512*2);
  US* Cm  = (US*)AA(1024L*1024*2);
  float* gvec = (float*)AA(1024*4);
  float* cb_f = (float*)AA(2048*4);
  float* fz_b = (float*)AA(512*4);
  float* rf_b = (float*)AA(512*4);
  float* h1_b = (float*)AA(512*4);
  float* h2_b = (float*)AA(256*4);
  float* bs_b = (float*)AA(512*4);
  float* gt_b = (float*)AA(512*4);
  float* wv_b = (float*)AA(2048*4);
  float* bngf = (float*)AA(512*4);
  float* bnbf = (float*)AA(512*4);
  float* pwf  = (float*)AA(2048*4);
  float* pbf  = (float*)AA(8*4);
  float* lngf = (float*)AA(512*4);
  float* lnbf = (float*)AA(512*4);
  float* feat = (float*)AA(16*256*4);
  float* dynA = (float*)AA(64*4);
  float* dynB = (float*)AA(64*4);
  float* psi  = (float*)AA((long)NB*4*SS*4);
  int* flag   = (int*)AA(64);
  if ((size_t)off > ws_size) return;
  US* h2    = cc;                 // [B,S,256]
  US* siluS = cc + 16777216;      // [B,S,D] (element offset; no overlap with h2)

  auto g1 = [](long n){ return dim3((unsigned)((n + 255)/256)); };
  const long sAct = (long)SS*DD*2;     // B batch stride bytes for [B,S,D]
  const long sPad = (long)SP*DD*2;
  const long sCC  = (long)SS*2048*2;
  const long oAct = (long)SS*DD;       // out batch stride, elements
  const long oCC  = (long)SS*2048;
  const long oH2  = (long)SS*HD;

  k_detect<<<1, 256, 0, stream>>>(x, flag);

  k_repack3<<<g1(2048L*512*3), 256, 0, stream>>>(conv_w, Wc, 2048, 512, flag);
  k_repack3<<<g1(512L*512*3), 256, 0, stream>>>(refine_w, Wr, 512, 512, flag);
  k_repack3<<<g1(512L*512*3), 256, 0, stream>>>(hyp1_w, Wh1, 512, 512, flag);
  k_repack3<<<g1(256L*512*3), 256, 0, stream>>>(hyp2_w, Wh2, 256, 512, flag);
  k_repack_wav<<<g1(4L*512*512), 256, 0, stream>>>(wav_w, Wwv, flag);
  k_cvt_b<<<g1(512L*2048), 256, 0, stream>>>(fusion_w, Fw, 512L*2048, flag);
  k_cvt_b<<<g1(512L*512), 256, 0, stream>>>(base_w, BW, 512L*512, flag);
  k_cvt_b<<<g1(512L*512), 256, 0, stream>>>(gate_w, GW, 512L*512, flag);
  k_cvt_f<<<g1(2048), 256, 0, stream>>>(conv_b, cb_f, 2048, flag);
  k_cvt_f<<<g1(512), 256, 0, stream>>>(fusion_b, fz_b, 512, flag);
  k_cvt_f<<<g1(512), 256, 0, stream>>>(refine_b, rf_b, 512, flag);
  k_cvt_f<<<g1(512), 256, 0, stream>>>(hyp1_b, h1_b, 512, flag);
  k_cvt_f<<<g1(256), 256, 0, stream>>>(hyp2_b, h2_b, 256, flag);
  k_cvt_f<<<g1(512), 256, 0, stream>>>(base_b, bs_b, 512, flag);
  k_cvt_f<<<g1(512), 256, 0, stream>>>(gate_b, gt_b, 512, flag);
  k_cvt_f<<<g1(2048), 256, 0, stream>>>(wav_b, wv_b, 2048, flag);
  k_cvt_f<<<g1(512), 256, 0, stream>>>(bn_g, bngf, 512, flag);
  k_cvt_f<<<g1(512), 256, 0, stream>>>(bn_b, bnbf, 512, flag);
  k_cvt_f<<<g1(2048), 256, 0, stream>>>(proj_w, pwf, 2048, flag);
  k_cvt_f<<<g1(8), 256, 0, stream>>>(proj_b, pbf, 8, flag);
  k_cvt_f<<<g1(512), 256, 0, stream>>>(ln_g, lngf, 512, flag);
  k_cvt_f<<<g1(512), 256, 0, stream>>>(ln_b, lnbf, 512, flag);
  k_build_g<<<g1(SS), 256, 0, stream>>>(gvec);
  k_build_cmat<<<g1((long)SS*SS), 256, 0, stream>>>(gvec, Cm);
  k_transpose_b<<<dim3(SS/32, DD/32, NB), 256, 0, stream>>>(x, xTh, flag);

  // ---- circulant low-pass: smA[b][s][d] = sum_s' Cm[s][s'] * x[b][s'][d] ----
  k_mfma<5,false><<<dim3(8,4,NB), 256, 0, stream>>>(Cm, xTh, smA,
      1024, 1024, (long)DD*SS*2, SS*2, 0, oAct, DD, 0,
      nullptr, nullptr, nullptr, nullptr, 0, 0);

  // ---- 2 iterations: 4 dilated convs (K=1536, gelu) -> concat -> fusion ----
  const int DIL[4] = {1, 2, 4, 8};
  US* cur = smA; US* nxt = smB;
  for (int it = 0; it < 2; ++it){
    k_pad_b<<<g1((long)NB*SP*128), 256, 0, stream>>>(cur, nullptr, padG, flag);
    for (int i = 0; i < 4; i++)
      k_mfma<1,true><<<dim3(4,8,NB), 256, 0, stream>>>(Wc + (long)i*512*1536, padG, cc,
          512, 1536, sPad, DD*2, DIL[i], oCC, 2048, i*512,
          cb_f + (long)i*512, nullptr, nullptr, nullptr, 0, 0);
    k_mfma<0,false><<<dim3(4,8,NB), 256, 0, stream>>>(Fw, cc, nxt,
        512, 2048, sCC, 4096, 0, oAct, DD, 0,
        fz_b, nullptr, nullptr, nullptr, 0, 0);
    US* t = cur; cur = nxt; nxt = t;   // after 2 iters: cur == smA
  }

  // ---- spike = refine(x - x_smooth) ----
  k_pad_b<<<g1((long)NB*SP*128), 256, 0, stream>>>(cur, x, padG, flag);
  k_mfma<0,true><<<dim3(4,8,NB), 256, 0, stream>>>(Wr, padG, smB,
      512, 1536, sPad, DD*2, 1, oAct, DD, 0, rf_b, nullptr, nullptr, nullptr, 0, 0);

  // ---- hypernet ----
  k_pad_b<<<g1((long)NB*SP*128), 256, 0, stream>>>(cur, nullptr, padG, flag);
  k_mfma<2,true><<<dim3(4,8,NB), 256, 0, stream>>>(Wh1, padG, xTh,
      512, 1536, sPad, DD*2, 1, oAct, DD, 0, h1_b, bngf, bnbf, nullptr, 0, 0);
  k_pad_b<<<g1((long)NB*SP*128), 256, 0, stream>>>(xTh, nullptr, padG, flag);
  k_mfma<3,true><<<dim3(2,8,NB), 256, 0, stream>>>(Wh2, padG, h2,
      256, 1536, sPad, DD*2, 1, oH2, HD, 0, h2_b, nullptr, nullptr, nullptr, 0, 0);
  k_pool<<<NB, 256, 0, stream>>>(h2, feat);
  k_params<<<1, 128, 0, stream>>>(feat, pwf, pbf, dynA, dynB);
  k_psi<<<g1(NB*4*SS), 256, 0, stream>>>(dynA, dynB, psi);

  // ---- base / gate / wavelet-KAN ----
  k_silu_b<<<g1((long)NB*SS*DD/4), 256, 0, stream>>>(cur, siluS);
  k_mfma<0,false><<<dim3(4,8,NB), 256, 0, stream>>>(BW, siluS, baseB,
      512, 512, sAct, DD*2, 0, oAct, DD, 0, bs_b, nullptr, nullptr, nullptr, 0, 0);
  k_mfma<0,false><<<dim3(4,8,NB), 256, 0, stream>>>(GW, baseB, padG,
      512, 512, sAct, DD*2, 0, oAct, DD, 0, gt_b, nullptr, nullptr, nullptr, 0, 0);
  for (int k = 0; k < 4; k++)
    k_mfma<4,false><<<dim3(4,8,NB), 256, 0, stream>>>(Wwv + (long)k*512*512, smB, kan,
        512, 512, sAct, DD*2, 0, oAct, DD, 0,
        wv_b + (long)k*512, nullptr, nullptr, psi + (long)k*SS, (long)4*SS, k == 0);

  // ---- combine + residual + LayerNorm ----
  k_final<<<NB*SS, 128, 0, stream>>>(baseB, kan, padG, x, d_out, lngf, lnbf, flag);
}

// Round 4
// 769.552 us; speedup vs baseline: 7.7211x; 1.1862x over previous
//
#include <hip/hip_runtime.h>
#include <hip/hip_bf16.h>
#include <math.h>

#define NB 16
#define SS 1024
#define DD 512
#define SP 1040   // S + 16 (edge pad of 8 both sides, covers max dilation 8)
#define HD 256

typedef unsigned short US;
typedef short bf16x8 __attribute__((ext_vector_type(8)));
typedef float f32x4 __attribute__((ext_vector_type(4)));
typedef __attribute__((address_space(1))) const void gv1;
typedef __attribute__((address_space(3))) void lv3;

static __device__ __forceinline__ float b2sf(US u){ return __uint_as_float(((unsigned)u)<<16); }
static __device__ __forceinline__ US f2b(float f){
  __hip_bfloat16 h = __float2bfloat16(f);
  union { __hip_bfloat16 h; US u; } c; c.h = h; return c.u;
}
static __device__ __forceinline__ float rd(const void* __restrict__ p, long i, int isf){
  return isf ? ((const float*)p)[i] : b2sf(((const US*)p)[i]);
}

// ---------------- dtype detection ----------------
__global__ void k_detect(const void* __restrict__ x, int* __restrict__ flag){
  const US* u = (const US*)x;
  int t = threadIdx.x;
  float m = 0.f;
  for (int i = t; i < 4096; i += 256){
    float v = fabsf(b2sf(u[i]));
    if (isnan(v) || isinf(v)) v = 1e30f;
    m = fmaxf(m, v);
  }
  for (int off = 32; off; off >>= 1) m = fmaxf(m, __shfl_down(m, off));
  __shared__ float sh[4];
  if ((t & 63) == 0) sh[t >> 6] = m;
  __syncthreads();
  if (t == 0){
    float mm = fmaxf(fmaxf(sh[0], sh[1]), fmaxf(sh[2], sh[3]));
    flag[0] = (mm > 1e6f) ? 1 : 0;
  }
}

// ---------------- converts / repacks ----------------
__global__ void k_cvt_f(const void* __restrict__ s, float* __restrict__ d, long n, const int* __restrict__ fl){
  int isf = fl[0];
  long i = (long)blockIdx.x*256 + threadIdx.x;
  if (i < n) d[i] = rd(s, i, isf);
}
__global__ void k_cvt_b(const void* __restrict__ s, US* __restrict__ d, long n, const int* __restrict__ fl){
  int isf = fl[0];
  long i = (long)blockIdx.x*256 + threadIdx.x;
  if (i < n) d[i] = f2b(rd(s, i, isf));
}
// src [O][C][3] -> dst [O][3*C] bf16 : dst[o][t*C+c] = src[o][c][t]
__global__ void k_repack3(const void* __restrict__ src, US* __restrict__ dst, int O, int C, const int* __restrict__ fl){
  int isf = fl[0];
  long i = (long)blockIdx.x*256 + threadIdx.x;
  long n = (long)O*3*C;
  if (i >= n) return;
  int o = (int)(i / (3*C)); int r = (int)(i - (long)o*3*C); int t = r / C; int c = r - t*C;
  dst[i] = f2b(rd(src, ((long)o*C + c)*3 + t, isf));
}
// wav_w [4][d][e] -> [4][e][d] bf16  (rows m=k*512+e, cols d)
__global__ void k_repack_wav(const void* __restrict__ src, US* __restrict__ dst, const int* __restrict__ fl){
  int isf = fl[0];
  long i = (long)blockIdx.x*256 + threadIdx.x;
  if (i >= 4L*DD*DD) return;
  int k = (int)(i >> 18); long r = i & ((1<<18)-1); int e = (int)(r >> 9); int d = (int)(r & 511);
  dst[i] = f2b(rd(src, ((long)(k*DD + d))*DD + e, isf));
}
// Dirichlet low-pass kernel
__global__ void k_build_g(float* __restrict__ g){
  int d = blockIdx.x*256 + threadIdx.x;
  if (d >= SS) return;
  float s = 1.f;
  for (int k = 1; k < 102; ++k){
    int r = (k*d) & (SS-1);
    s += 2.f * cosf(6.28318530718f * (float)r * (1.f/SS));
  }
  g[d] = s * (1.f/SS);
}
__global__ void k_build_cmat(const float* __restrict__ g, US* __restrict__ cm){
  int i = blockIdx.x*256 + threadIdx.x;
  if (i >= SS*SS) return;
  int t = i >> 10, s = i & (SS-1);
  cm[i] = f2b(g[(s - t) & (SS-1)]);
}
// x [B,S,D] -> xT [B,D,S] bf16
__global__ __launch_bounds__(256) void k_transpose_b(const void* __restrict__ x, US* __restrict__ xt, const int* __restrict__ fl){
  int isf = fl[0];
  __shared__ float tl[32][33];
  int b = blockIdx.z, s0 = blockIdx.x*32, d0 = blockIdx.y*32;
  int tx = threadIdx.x & 31, ty = threadIdx.x >> 5;
  for (int i = ty; i < 32; i += 8)
    tl[i][tx] = rd(x, ((long)(b*SS + s0+i))*DD + d0+tx, isf);
  __syncthreads();
  for (int i = ty; i < 32; i += 8)
    xt[((long)(b*DD + d0+i))*SS + s0+tx] = f2b(tl[tx][i]);
}
// edge pad rows: dst[b][j][d] = src[b][clamp(j-8)][d]  (or x - src when xsub)
__global__ void k_pad_b(const US* __restrict__ src, const void* __restrict__ xsub, US* __restrict__ dst, const int* __restrict__ fl){
  long i = (long)blockIdx.x*256 + threadIdx.x;   // 4-elem chunks
  const long TOT = (long)NB*SP*128;
  if (i >= TOT) return;
  int c4 = (int)(i & 127);
  int j  = (int)((i >> 7) % SP);
  int b  = (int)(i / (128L*SP));
  int sr = j - 8; sr = sr < 0 ? 0 : (sr > SS-1 ? SS-1 : sr);
  long si = ((long)(b*SS + sr))*DD + c4*4;
  ushort4 sv = *(const ushort4*)&src[si];
  float v0=b2sf(sv.x), v1=b2sf(sv.y), v2=b2sf(sv.z), v3=b2sf(sv.w);
  if (xsub){
    if (fl[0]){
      float4 xv = *(const float4*)((const float*)xsub + si);
      v0 = xv.x - v0; v1 = xv.y - v1; v2 = xv.z - v2; v3 = xv.w - v3;
    } else {
      ushort4 xv = *(const ushort4*)((const US*)xsub + si);
      v0 = b2sf(xv.x) - v0; v1 = b2sf(xv.y) - v1; v2 = b2sf(xv.z) - v2; v3 = b2sf(xv.w) - v3;
    }
  }
  ushort4 o; o.x=f2b(v0); o.y=f2b(v1); o.z=f2b(v2); o.w=f2b(v3);
  *(ushort4*)&dst[((long)(b*SP + j))*DD + c4*4] = o;
}
__global__ void k_silu_b(const US* __restrict__ s, US* __restrict__ d){
  long i = (long)blockIdx.x*256 + threadIdx.x;
  if (i >= (long)NB*SS*DD/4) return;
  ushort4 sv = *(const ushort4*)&s[i*4];
  float v[4] = {b2sf(sv.x), b2sf(sv.y), b2sf(sv.z), b2sf(sv.w)};
  ushort4 o;
  US* op = (US*)&o;
  #pragma unroll
  for (int r = 0; r < 4; r++){ float t = v[r]; op[r] = f2b(t/(1.f + expf(-t))); }
  *(ushort4*)&d[i*4] = o;
}

// ---------------- MFMA GEMM ----------------
// C[m][n] = sum_k A[m][k] * Bt[n][k], batched.
// Grid: blockIdx.x = ny + NYB*b (B-panel id; same panel -> same XCD),
//       blockIdx.y = mx (panel-sharing axis; linear stride NYB*NB % 8 == 0).
// dil < 0 => per-m-tile dilation 1<<(m0>>9) (merged 4-dilation conv).
// EPI: 0=bias+store bf16 out[b][n][moff+m]; 1=+gelu; 2=+bn+silu; 3=+silu;
//      5=NT store bf16 out[b][m][n], no bias.
template<int EPI, bool TAPPED>
__global__ __launch_bounds__(256) void k_mfma(
    const US* __restrict__ A, const US* __restrict__ Bact, void* __restrict__ Out,
    int NYB, int K, long sBbytes, int ldbB, int dil,
    long sOut, int ldo, int moff,
    const float* __restrict__ bias, const float* __restrict__ s1v, const float* __restrict__ s2v)
{
  __shared__ alignas(16) US As[128*64];
  __shared__ alignas(16) US Bs[128*64];
  const int bx = blockIdx.x;
  const int ny = bx % NYB;
  const int b  = bx / NYB;
  const int m0 = blockIdx.y*128, n0 = ny*128;
  const int dd = (TAPPED && dil < 0) ? (1 << (m0 >> 9)) : dil;
  const char* Bb = (const char*)Bact + (long)b*sBbytes;
  const int tid = threadIdx.x;
  const int lane = tid & 63, w = tid >> 6;
  const int wr = w >> 1, wc = w & 1;
  const int col = lane & 15, g = lane >> 4;

  f32x4 acc[4][4] = {};

  int rows_[4], sls_[4];
  #pragma unroll
  for (int i = 0; i < 4; i++){
    int c = w*256 + i*64 + lane;
    rows_[i] = c >> 3;
    sls_[i] = (c & 7) ^ ((c >> 3) & 7);
  }

  for (int k0 = 0; k0 < K; k0 += 64){
    const int c0 = TAPPED ? (k0 & 511) : k0;
    const int srowOff = TAPPED ? (8 + ((k0 >> 9) - 1)*dd) : 0;
    __syncthreads();   // previous iter's LDS reads done
    #pragma unroll
    for (int i = 0; i < 4; i++){
      const char* ga = (const char*)A + ((long)(m0 + rows_[i])*K + k0)*2 + sls_[i]*16;
      __builtin_amdgcn_global_load_lds((gv1*)ga, (lv3*)&As[(w*256 + i*64)*8], 16, 0, 0);
      const char* gb = Bb + (long)(n0 + rows_[i] + srowOff)*ldbB + c0*2 + sls_[i]*16;
      __builtin_amdgcn_global_load_lds((gv1*)gb, (lv3*)&Bs[(w*256 + i*64)*8], 16, 0, 0);
    }
    __syncthreads();   // vmcnt(0) drained by compiler before barrier
    #pragma unroll
    for (int kk = 0; kk < 2; kk++){
      bf16x8 af[4], bf[4];
      #pragma unroll
      for (int f = 0; f < 4; f++){
        int rowa = wr*64 + f*16 + col;
        int sla = (g + kk*4) ^ (rowa & 7);
        af[f] = *(const bf16x8*)&As[rowa*64 + sla*8];
        int rowb = wc*64 + f*16 + col;
        int slb = (g + kk*4) ^ (rowb & 7);
        bf[f] = *(const bf16x8*)&Bs[rowb*64 + slb*8];
      }
      #pragma unroll
      for (int fm = 0; fm < 4; fm++)
        #pragma unroll
        for (int fn = 0; fn < 4; fn++)
          acc[fm][fn] = __builtin_amdgcn_mfma_f32_16x16x32_bf16(af[fm], bf[fn], acc[fm][fn], 0, 0, 0);
    }
  }

  // epilogue
  #pragma unroll
  for (int fm = 0; fm < 4; fm++){
    const int mm = m0 + wr*64 + fm*16 + g*4;   // 4 consecutive m per lane
    #pragma unroll
    for (int fn = 0; fn < 4; fn++){
      const int nn = n0 + wc*64 + fn*16 + col;
      f32x4 v = acc[fm][fn];
      if (EPI == 5){
        US* o = (US*)Out + (long)b*sOut + (long)mm*ldo + nn;
        #pragma unroll
        for (int r = 0; r < 4; r++) o[(long)r*ldo] = f2b(v[r]);
      } else {
        US pk[4];
        #pragma unroll
        for (int r = 0; r < 4; r++){
          int m = mm + r;
          float val = v[r] + bias[m];
          if (EPI == 1) val = 0.5f*val*(1.f + erff(val*0.70710678f));
          if (EPI == 2){ val = val*(s1v[m]*0.99999500f) + s2v[m]; val = val/(1.f + expf(-val)); }
          if (EPI == 3){ val = val/(1.f + expf(-val)); }
          pk[r] = f2b(val);
        }
        US* o = (US*)Out + (long)b*sOut + (long)nn*ldo + moff + mm;
        *(ushort4*)o = *(ushort4*)pk;
      }
    }
  }
}

// ---------------- small tail kernels ----------------
__global__ __launch_bounds__(256) void k_pool(const US* __restrict__ h2, float* __restrict__ feat){
  int b = blockIdx.x, c = threadIdx.x;
  float s = 0.f;
  for (int t = 0; t < SS; t++) s += b2sf(h2[((long)(b*SS + t))*HD + c]);
  feat[b*HD + c] = s * (1.f/SS);
}
__global__ void k_params(const float* __restrict__ feat, const float* __restrict__ pw,
                         const float* __restrict__ pb, float* __restrict__ dynA, float* __restrict__ dynB){
  int t = threadIdx.x;
  if (t >= 128) return;
  int b = t >> 3, j = t & 7;
  float s = pb[j];
  for (int c = 0; c < HD; c++) s += feat[b*HD + c]*pw[j*HD + c];
  int k = j >> 1;
  if ((j & 1) == 0){
    float sp = s > 20.f ? s : log1pf(expf(s));
    dynA[b*4 + k] = sp + 0.01f;
  } else {
    dynB[b*4 + k] = 1024.f/(1.f + expf(-s));
  }
}
// psi[b][k][s]
__global__ void k_psi(const float* __restrict__ dynA, const float* __restrict__ dynB, float* __restrict__ psi){
  int i = blockIdx.x*256 + threadIdx.x;
  if (i >= NB*4*SS) return;
  int b = i >> 12, k = (i >> 10) & 3, s = i & (SS-1);
  float u = ((float)s - dynB[b*4 + k]) / dynA[b*4 + k];
  psi[i] = 0.86732507f*(1.f - u*u)*expf(-0.5f*u*u);
}
// y = base + (sum_k psi_k * zz_k)*2*sigmoid(gate) + x; LayerNorm over D
__global__ __launch_bounds__(128) void k_final(const US* __restrict__ base, const US* __restrict__ zz,
    const US* __restrict__ gate, const float* __restrict__ psi, const void* __restrict__ x,
    void* __restrict__ out, const float* __restrict__ lng, const float* __restrict__ lnb,
    const int* __restrict__ fl){
  int isf = fl[0];
  long row = blockIdx.x;               // b*S + s
  int b = (int)(row >> 10), s = (int)(row & (SS-1));
  int t = threadIdx.x;
  long off = row*DD + t*4;
  ushort4 bs = *(const ushort4*)&base[off];
  ushort4 gt = *(const ushort4*)&gate[off];
  float p0 = psi[b*4096 + s];
  float p1 = psi[b*4096 + 1024 + s];
  float p2 = psi[b*4096 + 2048 + s];
  float p3 = psi[b*4096 + 3072 + s];
  const US* zrow = zz + row*2048 + t*4;
  ushort4 z0 = *(const ushort4*)&zrow[0];
  ushort4 z1 = *(const ushort4*)&zrow[512];
  ushort4 z2 = *(const ushort4*)&zrow[1024];
  ushort4 z3 = *(const ushort4*)&zrow[1536];
  float xv[4];
  if (isf){ float4 q = *(const float4*)((const float*)x + off); xv[0]=q.x; xv[1]=q.y; xv[2]=q.z; xv[3]=q.w; }
  else { ushort4 q = *(const ushort4*)((const US*)x + off); xv[0]=b2sf(q.x); xv[1]=b2sf(q.y); xv[2]=b2sf(q.z); xv[3]=b2sf(q.w); }
  float bv[4] = {b2sf(bs.x), b2sf(bs.y), b2sf(bs.z), b2sf(bs.w)};
  float gv[4] = {b2sf(gt.x), b2sf(gt.y), b2sf(gt.z), b2sf(gt.w)};
  const US* z0p = (const US*)&z0; const US* z1p = (const US*)&z1;
  const US* z2p = (const US*)&z2; const US* z3p = (const US*)&z3;
  float y[4];
  float sm = 0.f, ssq = 0.f;
  #pragma unroll
  for (int r = 0; r < 4; r++){
    float kan = p0*b2sf(z0p[r]) + p1*b2sf(z1p[r]) + p2*b2sf(z2p[r]) + p3*b2sf(z3p[r]);
    float amp = 2.f/(1.f + expf(-gv[r]));
    y[r] = bv[r] + kan*amp + xv[r];
    sm += y[r]; ssq += y[r]*y[r];
  }
  for (int o = 32; o; o >>= 1){ sm += __shfl_down(sm, o); ssq += __shfl_down(ssq, o); }
  __shared__ float sh[4];
  int lane = t & 63, wid = t >> 6;
  if (lane == 0){ sh[wid*2] = sm; sh[wid*2+1] = ssq; }
  __syncthreads();
  float S1 = sh[0] + sh[2], S2 = sh[1] + sh[3];
  float mean = S1*(1.f/DD), var = S2*(1.f/DD) - mean*mean;
  float rstd = rsqrtf(var + 1e-5f);
  #pragma unroll
  for (int r = 0; r < 4; r++){
    int d = t*4 + r;
    float val = (y[r] - mean)*rstd*lng[d] + lnb[d];
    if (isf) ((float*)out)[off + r] = val;
    else     ((US*)out)[off + r] = f2b(val);
  }
}

extern "C" void kernel_launch(void* const* d_in, const int* in_sizes, int n_in,
                              void* d_out, int out_size, void* d_ws, size_t ws_size,
                              hipStream_t stream){
  const void* x       = d_in[0];
  const void* conv_w  = d_in[1];
  const void* conv_b  = d_in[2];
  const void* fusion_w= d_in[3];
  const void* fusion_b= d_in[4];
  const void* refine_w= d_in[5];
  const void* refine_b= d_in[6];
  const void* hyp1_w  = d_in[7];
  const void* hyp1_b  = d_in[8];
  const void* bn_g    = d_in[9];
  const void* bn_b    = d_in[10];
  const void* hyp2_w  = d_in[11];
  const void* hyp2_b  = d_in[12];
  const void* proj_w  = d_in[13];
  const void* proj_b  = d_in[14];
  const void* gate_w  = d_in[15];
  const void* gate_b  = d_in[16];
  const void* base_w  = d_in[17];
  const void* base_b  = d_in[18];
  const void* wav_w   = d_in[19];
  const void* wav_b   = d_in[20];
  const void* ln_g    = d_in[21];
  const void* ln_b    = d_in[22];

  char* wsb = (char*)d_ws;
  long off = 0;
  auto AA = [&](long bytes)->char*{ char* p = wsb + off; off += (bytes + 255) & ~255L; return p; };
  US* padG  = (US*)AA((long)NB*SP*DD*2);   // pad buffer, later gate
  US* smA   = (US*)AA((long)NB*SS*DD*2);   // x_smooth ping
  US* smB   = (US*)AA((long)NB*SS*DD*2);   // x_smooth pong / spike
  US* xTh   = (US*)AA((long)NB*SS*DD*2);   // xT, later h1
  US* cc    = (US*)AA((long)NB*SS*2048*2); // concat / h2+siluS / zz
  US* baseB = (US*)AA((long)NB*SS*DD*2);
  US* Wc  = (US*)AA(4L*512*1536*2);        // [2048][1536]
  US* Wr  = (US*)AA(512L*1536*2);
  US* Wh1 = (US*)AA(512L*1536*2);
  US* Wh2 = (US*)AA(256L*1536*2);
  US* Wwv = (US*)AA(4L*512*512*2);         // [2048][512]
  US* Fw  = (US*)AA(512L*2048*2);
  US* BW  = (US*)AA(512L*512*2);
  US* GW  = (US*)AA(512L*512*2);
  US* Cm  = (US*)AA(1024L*1024*2);
  float* gvec = (float*)AA(1024*4);
  float* cb_f = (float*)AA(2048*4);
  float* fz_b = (float*)AA(512*4);
  float* rf_b = (float*)AA(512*4);
  float* h1_b = (float*)AA(512*4);
  float* h2_b = (float*)AA(256*4);
  float* bs_b = (float*)AA(512*4);
  float* gt_b = (float*)AA(512*4);
  float* wv_b = (float*)AA(2048*4);
  float* bngf = (float*)AA(512*4);
  float* bnbf = (float*)AA(512*4);
  float* pwf  = (float*)AA(2048*4);
  float* pbf  = (float*)AA(8*4);
  float* lngf = (float*)AA(512*4);
  float* lnbf = (float*)AA(512*4);
  float* feat = (float*)AA(16*256*4);
  float* dynA = (float*)AA(64*4);
  float* dynB = (float*)AA(64*4);
  float* psi  = (float*)AA((long)NB*4*SS*4);
  int* flag   = (int*)AA(64);
  if ((size_t)off > ws_size) return;
  US* h2    = cc;                 // [B,S,256]
  US* siluS = cc + 16777216;      // [B,S,D]

  auto g1 = [](long n){ return dim3((unsigned)((n + 255)/256)); };
  const long sAct = (long)SS*DD*2;     // batch stride bytes for [B,S,D]
  const long sPad = (long)SP*DD*2;
  const long sCC  = (long)SS*2048*2;
  const long oAct = (long)SS*DD;       // out batch stride, elements
  const long oCC  = (long)SS*2048;
  const long oH2  = (long)SS*HD;

  k_detect<<<1, 256, 0, stream>>>(x, flag);

  k_repack3<<<g1(2048L*512*3), 256, 0, stream>>>(conv_w, Wc, 2048, 512, flag);
  k_repack3<<<g1(512L*512*3), 256, 0, stream>>>(refine_w, Wr, 512, 512, flag);
  k_repack3<<<g1(512L*512*3), 256, 0, stream>>>(hyp1_w, Wh1, 512, 512, flag);
  k_repack3<<<g1(256L*512*3), 256, 0, stream>>>(hyp2_w, Wh2, 256, 512, flag);
  k_repack_wav<<<g1(4L*512*512), 256, 0, stream>>>(wav_w, Wwv, flag);
  k_cvt_b<<<g1(512L*2048), 256, 0, stream>>>(fusion_w, Fw, 512L*2048, flag);
  k_cvt_b<<<g1(512L*512), 256, 0, stream>>>(base_w, BW, 512L*512, flag);
  k_cvt_b<<<g1(512L*512), 256, 0, stream>>>(gate_w, GW, 512L*512, flag);
  k_cvt_f<<<g1(2048), 256, 0, stream>>>(conv_b, cb_f, 2048, flag);
  k_cvt_f<<<g1(512), 256, 0, stream>>>(fusion_b, fz_b, 512, flag);
  k_cvt_f<<<g1(512), 256, 0, stream>>>(refine_b, rf_b, 512, flag);
  k_cvt_f<<<g1(512), 256, 0, stream>>>(hyp1_b, h1_b, 512, flag);
  k_cvt_f<<<g1(256), 256, 0, stream>>>(hyp2_b, h2_b, 256, flag);
  k_cvt_f<<<g1(512), 256, 0, stream>>>(base_b, bs_b, 512, flag);
  k_cvt_f<<<g1(512), 256, 0, stream>>>(gate_b, gt_b, 512, flag);
  k_cvt_f<<<g1(2048), 256, 0, stream>>>(wav_b, wv_b, 2048, flag);
  k_cvt_f<<<g1(512), 256, 0, stream>>>(bn_g, bngf, 512, flag);
  k_cvt_f<<<g1(512), 256, 0, stream>>>(bn_b, bnbf, 512, flag);
  k_cvt_f<<<g1(2048), 256, 0, stream>>>(proj_w, pwf, 2048, flag);
  k_cvt_f<<<g1(8), 256, 0, stream>>>(proj_b, pbf, 8, flag);
  k_cvt_f<<<g1(512), 256, 0, stream>>>(ln_g, lngf, 512, flag);
  k_cvt_f<<<g1(512), 256, 0, stream>>>(ln_b, lnbf, 512, flag);
  k_build_g<<<g1(SS), 256, 0, stream>>>(gvec);
  k_build_cmat<<<g1((long)SS*SS), 256, 0, stream>>>(gvec, Cm);
  k_transpose_b<<<dim3(SS/32, DD/32, NB), 256, 0, stream>>>(x, xTh, flag);

  // ---- circulant low-pass: smA[b][s][d] = sum_s' Cm[s][s'] * xT[b][d][s'] ----
  k_mfma<5,false><<<dim3(4*NB, 8), 256, 0, stream>>>(Cm, xTh, smA,
      4, 1024, (long)DD*SS*2, SS*2, 0, oAct, DD, 0, nullptr, nullptr, nullptr);

  // ---- 2 iterations: merged 4-dilation conv (K=1536, gelu) -> fusion ----
  US* cur = smA; US* nxt = smB;
  for (int it = 0; it < 2; ++it){
    k_pad_b<<<g1((long)NB*SP*128), 256, 0, stream>>>(cur, nullptr, padG, flag);
    k_mfma<1,true><<<dim3(8*NB, 16), 256, 0, stream>>>(Wc, padG, cc,
        8, 1536, sPad, DD*2, -1, oCC, 2048, 0, cb_f, nullptr, nullptr);
    k_mfma<0,false><<<dim3(8*NB, 4), 256, 0, stream>>>(Fw, cc, nxt,
        8, 2048, sCC, 4096, 0, oAct, DD, 0, fz_b, nullptr, nullptr);
    US* t = cur; cur = nxt; nxt = t;   // after 2 iters: cur == smA
  }

  // ---- spike = refine(x - x_smooth) ----
  k_pad_b<<<g1((long)NB*SP*128), 256, 0, stream>>>(cur, x, padG, flag);
  k_mfma<0,true><<<dim3(8*NB, 4), 256, 0, stream>>>(Wr, padG, smB,
      8, 1536, sPad, DD*2, 1, oAct, DD, 0, rf_b, nullptr, nullptr);

  // ---- hypernet ----
  k_pad_b<<<g1((long)NB*SP*128), 256, 0, stream>>>(cur, nullptr, padG, flag);
  k_mfma<2,true><<<dim3(8*NB, 4), 256, 0, stream>>>(Wh1, padG, xTh,
      8, 1536, sPad, DD*2, 1, oAct, DD, 0, h1_b, bngf, bnbf);
  k_pad_b<<<g1((long)NB*SP*128), 256, 0, stream>>>(xTh, nullptr, padG, flag);
  k_mfma<3,true><<<dim3(8*NB, 2), 256, 0, stream>>>(Wh2, padG, h2,
      8, 1536, sPad, DD*2, 1, oH2, HD, 0, h2_b, nullptr, nullptr);
  k_pool<<<NB, 256, 0, stream>>>(h2, feat);
  k_params<<<1, 128, 0, stream>>>(feat, pwf, pbf, dynA, dynB);
  k_psi<<<g1(NB*4*SS), 256, 0, stream>>>(dynA, dynB, psi);

  // ---- base / gate ----
  k_silu_b<<<g1((long)NB*SS*DD/4), 256, 0, stream>>>(cur, siluS);
  k_mfma<0,false><<<dim3(8*NB, 4), 256, 0, stream>>>(BW, siluS, baseB,
      8, 512, sAct, DD*2, 0, oAct, DD, 0, bs_b, nullptr, nullptr);
  k_mfma<0,false><<<dim3(8*NB, 4), 256, 0, stream>>>(GW, baseB, padG,
      8, 512, sAct, DD*2, 0, oAct, DD, 0, gt_b, nullptr, nullptr);

  // ---- merged wavelet GEMM: zz[b][s][k*512+e] = spike @ Wwv_k^T + wav_b ----
  k_mfma<0,false><<<dim3(8*NB, 16), 256, 0, stream>>>(Wwv, smB, cc,
      8, 512, sAct, DD*2, 0, oCC, 2048, 0, wv_b, nullptr, nullptr);

  // ---- combine + residual + LayerNorm ----
  k_final<<<NB*SS, 128, 0, stream>>>(baseB, cc, padG, psi, x, d_out, lngf, lnbf, flag);
}

// Round 5
// 767.249 us; speedup vs baseline: 7.7442x; 1.0030x over previous
//
#include <hip/hip_runtime.h>
#include <hip/hip_bf16.h>
#include <math.h>

#define NB 16
#define SS 1024
#define DD 512
#define SP 1040   // S + 16 (edge pad of 8 both sides, covers max dilation 8)
#define HD 256

typedef unsigned short US;
typedef short bf16x8 __attribute__((ext_vector_type(8)));
typedef float f32x4 __attribute__((ext_vector_type(4)));
typedef __attribute__((address_space(1))) const void gv1;
typedef __attribute__((address_space(3))) void lv3;

static __device__ __forceinline__ float b2sf(US u){ return __uint_as_float(((unsigned)u)<<16); }
static __device__ __forceinline__ US f2b(float f){
  __hip_bfloat16 h = __float2bfloat16(f);
  union { __hip_bfloat16 h; US u; } c; c.h = h; return c.u;
}
static __device__ __forceinline__ float rd(const void* __restrict__ p, long i, int isf){
  return isf ? ((const float*)p)[i] : b2sf(((const US*)p)[i]);
}

// ---------------- dtype detection ----------------
__global__ void k_detect(const void* __restrict__ x, int* __restrict__ flag){
  const US* u = (const US*)x;
  int t = threadIdx.x;
  float m = 0.f;
  for (int i = t; i < 4096; i += 256){
    float v = fabsf(b2sf(u[i]));
    if (isnan(v) || isinf(v)) v = 1e30f;
    m = fmaxf(m, v);
  }
  for (int off = 32; off; off >>= 1) m = fmaxf(m, __shfl_down(m, off));
  __shared__ float sh[4];
  if ((t & 63) == 0) sh[t >> 6] = m;
  __syncthreads();
  if (t == 0){
    float mm = fmaxf(fmaxf(sh[0], sh[1]), fmaxf(sh[2], sh[3]));
    flag[0] = (mm > 1e6f) ? 1 : 0;
  }
}

// ---------------- converts / repacks ----------------
__global__ void k_cvt_f(const void* __restrict__ s, float* __restrict__ d, long n, const int* __restrict__ fl){
  int isf = fl[0];
  long i = (long)blockIdx.x*256 + threadIdx.x;
  if (i < n) d[i] = rd(s, i, isf);
}
__global__ void k_cvt_b(const void* __restrict__ s, US* __restrict__ d, long n, const int* __restrict__ fl){
  int isf = fl[0];
  long i = (long)blockIdx.x*256 + threadIdx.x;
  if (i < n) d[i] = f2b(rd(s, i, isf));
}
// src [O][C][3] -> dst [O][3*C] bf16 : dst[o][t*C+c] = src[o][c][t]
__global__ void k_repack3(const void* __restrict__ src, US* __restrict__ dst, int O, int C, const int* __restrict__ fl){
  int isf = fl[0];
  long i = (long)blockIdx.x*256 + threadIdx.x;
  long n = (long)O*3*C;
  if (i >= n) return;
  int o = (int)(i / (3*C)); int r = (int)(i - (long)o*3*C); int t = r / C; int c = r - t*C;
  dst[i] = f2b(rd(src, ((long)o*C + c)*3 + t, isf));
}
// wav_w [4][d][e] -> [4][e][d] bf16  (rows m=k*512+e, cols d)
__global__ void k_repack_wav(const void* __restrict__ src, US* __restrict__ dst, const int* __restrict__ fl){
  int isf = fl[0];
  long i = (long)blockIdx.x*256 + threadIdx.x;
  if (i >= 4L*DD*DD) return;
  int k = (int)(i >> 18); long r = i & ((1<<18)-1); int e = (int)(r >> 9); int d = (int)(r & 511);
  dst[i] = f2b(rd(src, ((long)(k*DD + d))*DD + e, isf));
}
// Dirichlet low-pass kernel
__global__ void k_build_g(float* __restrict__ g){
  int d = blockIdx.x*256 + threadIdx.x;
  if (d >= SS) return;
  float s = 1.f;
  for (int k = 1; k < 102; ++k){
    int r = (k*d) & (SS-1);
    s += 2.f * cosf(6.28318530718f * (float)r * (1.f/SS));
  }
  g[d] = s * (1.f/SS);
}
__global__ void k_build_cmat(const float* __restrict__ g, US* __restrict__ cm){
  int i = blockIdx.x*256 + threadIdx.x;
  if (i >= SS*SS) return;
  int t = i >> 10, s = i & (SS-1);
  cm[i] = f2b(g[(s - t) & (SS-1)]);
}
// x [B,S,D] -> xT [B,D,S] bf16
__global__ __launch_bounds__(256) void k_transpose_b(const void* __restrict__ x, US* __restrict__ xt, const int* __restrict__ fl){
  int isf = fl[0];
  __shared__ float tl[32][33];
  int b = blockIdx.z, s0 = blockIdx.x*32, d0 = blockIdx.y*32;
  int tx = threadIdx.x & 31, ty = threadIdx.x >> 5;
  for (int i = ty; i < 32; i += 8)
    tl[i][tx] = rd(x, ((long)(b*SS + s0+i))*DD + d0+tx, isf);
  __syncthreads();
  for (int i = ty; i < 32; i += 8)
    xt[((long)(b*DD + d0+i))*SS + s0+tx] = f2b(tl[tx][i]);
}
// edge pad rows: dst[b][j][d] = src[b][clamp(j-8)][d]  (or x - src when xsub)
__global__ void k_pad_b(const US* __restrict__ src, const void* __restrict__ xsub, US* __restrict__ dst, const int* __restrict__ fl){
  long i = (long)blockIdx.x*256 + threadIdx.x;   // 4-elem chunks
  const long TOT = (long)NB*SP*128;
  if (i >= TOT) return;
  int c4 = (int)(i & 127);
  int j  = (int)((i >> 7) % SP);
  int b  = (int)(i / (128L*SP));
  int sr = j - 8; sr = sr < 0 ? 0 : (sr > SS-1 ? SS-1 : sr);
  long si = ((long)(b*SS + sr))*DD + c4*4;
  ushort4 sv = *(const ushort4*)&src[si];
  float v0=b2sf(sv.x), v1=b2sf(sv.y), v2=b2sf(sv.z), v3=b2sf(sv.w);
  if (xsub){
    if (fl[0]){
      float4 xv = *(const float4*)((const float*)xsub + si);
      v0 = xv.x - v0; v1 = xv.y - v1; v2 = xv.z - v2; v3 = xv.w - v3;
    } else {
      ushort4 xv = *(const ushort4*)((const US*)xsub + si);
      v0 = b2sf(xv.x) - v0; v1 = b2sf(xv.y) - v1; v2 = b2sf(xv.z) - v2; v3 = b2sf(xv.w) - v3;
    }
  }
  ushort4 o; o.x=f2b(v0); o.y=f2b(v1); o.z=f2b(v2); o.w=f2b(v3);
  *(ushort4*)&dst[((long)(b*SP + j))*DD + c4*4] = o;
}
__global__ void k_silu_b(const US* __restrict__ s, US* __restrict__ d){
  long i = (long)blockIdx.x*256 + threadIdx.x;
  if (i >= (long)NB*SS*DD/4) return;
  ushort4 sv = *(const ushort4*)&s[i*4];
  float v[4] = {b2sf(sv.x), b2sf(sv.y), b2sf(sv.z), b2sf(sv.w)};
  ushort4 o;
  US* op = (US*)&o;
  #pragma unroll
  for (int r = 0; r < 4; r++){ float t = v[r]; op[r] = f2b(t/(1.f + expf(-t))); }
  *(ushort4*)&d[i*4] = o;
}

// ---------------- MFMA GEMM ----------------
// C[m][n] = sum_k A[m][k] * Bt[n][k], batched.
// Grid: blockIdx.x = ny + NYB*b (B-panel id; same panel -> same XCD),
//       blockIdx.y = mx (panel-sharing axis; linear stride NYB*NB % 8 == 0).
// dil < 0 => per-m-tile dilation 1<<(m0>>9) (merged 4-dilation conv).
// EPI: 0=bias, store bf16 out[b][n][moff+m]; 1=+gelu; 2=+bn+silu; 3=+silu;
//      4=wavelet-fused: 4 K-chunks, facc += psi_k[n]*(acc+bias_k[m]), store bf16 out[b][n][m];
//      5=NT store bf16 out[b][m][n], no bias.
// All stores go through an LDS-staged tile -> 16B dwordx4 coalesced global stores.
template<int EPI, bool TAPPED>
__global__ __launch_bounds__(256) void k_mfma(
    const US* __restrict__ A, const US* __restrict__ Bact, void* __restrict__ Out,
    int NYB, int K, long sBbytes, int ldbB, int dil,
    long sOut, int ldo, int moff,
    const float* __restrict__ bias, const float* __restrict__ s1v, const float* __restrict__ s2v,
    const float* __restrict__ psiP)
{
  __shared__ alignas(16) US shb[2*128*64];   // As | Bs, reused as 32KB out-tile
  __shared__ float psh[(EPI==4) ? 512 : 4];
  US* As = shb;
  US* Bs = shb + 128*64;
  const int bx = blockIdx.x;
  const int ny = bx % NYB;
  const int b  = bx / NYB;
  const int m0 = blockIdx.y*128, n0 = ny*128;
  const int dd = (TAPPED && dil < 0) ? (1 << (m0 >> 9)) : dil;
  const char* Bb = (const char*)Bact + (long)b*sBbytes;
  const int tid = threadIdx.x;
  const int lane = tid & 63, w = tid >> 6;
  const int wr = w >> 1, wc = w & 1;
  const int col = lane & 15, g = lane >> 4;

  if (EPI == 4){
    for (int i = tid; i < 512; i += 256)
      psh[i] = psiP[(long)b*4096 + (i >> 7)*SS + n0 + (i & 127)];
    // consumed only after the first K-chunk's barriers
  }

  f32x4 acc[4][4];
  f32x4 facc[4][4];
  if (EPI == 4){
    #pragma unroll
    for (int i = 0; i < 4; i++)
      #pragma unroll
      for (int j = 0; j < 4; j++) facc[i][j] = (f32x4){0.f,0.f,0.f,0.f};
  }

  int rows_[4], sls_[4];
  #pragma unroll
  for (int i = 0; i < 4; i++){
    int c = w*256 + i*64 + lane;
    rows_[i] = c >> 3;
    sls_[i] = (c & 7) ^ ((c >> 3) & 7);
  }

  const int NKC = (EPI == 4) ? 4 : 1;
  for (int kc = 0; kc < NKC; ++kc){
    #pragma unroll
    for (int i = 0; i < 4; i++)
      #pragma unroll
      for (int j = 0; j < 4; j++) acc[i][j] = (f32x4){0.f,0.f,0.f,0.f};

    for (int k0 = 0; k0 < K; k0 += 64){
      const int c0 = TAPPED ? (k0 & 511) : k0;
      const int srowOff = TAPPED ? (8 + ((k0 >> 9) - 1)*dd) : 0;
      __syncthreads();   // previous iter's LDS reads done
      #pragma unroll
      for (int i = 0; i < 4; i++){
        const long arow = (long)(m0 + rows_[i]) + (EPI==4 ? kc*512 : 0);
        const char* ga = (const char*)A + (arow*K + k0)*2 + sls_[i]*16;
        __builtin_amdgcn_global_load_lds((gv1*)ga, (lv3*)&As[(w*256 + i*64)*8], 16, 0, 0);
        const char* gb = Bb + (long)(n0 + rows_[i] + srowOff)*ldbB + c0*2 + sls_[i]*16;
        __builtin_amdgcn_global_load_lds((gv1*)gb, (lv3*)&Bs[(w*256 + i*64)*8], 16, 0, 0);
      }
      __syncthreads();   // vmcnt(0) drained by compiler before barrier
      #pragma unroll
      for (int kk = 0; kk < 2; kk++){
        bf16x8 af[4], bf[4];
        #pragma unroll
        for (int f = 0; f < 4; f++){
          int rowa = wr*64 + f*16 + col;
          int sla = (g + kk*4) ^ (rowa & 7);
          af[f] = *(const bf16x8*)&As[rowa*64 + sla*8];
          int rowb = wc*64 + f*16 + col;
          int slb = (g + kk*4) ^ (rowb & 7);
          bf[f] = *(const bf16x8*)&Bs[rowb*64 + slb*8];
        }
        #pragma unroll
        for (int fm = 0; fm < 4; fm++)
          #pragma unroll
          for (int fn = 0; fn < 4; fn++)
            acc[fm][fn] = __builtin_amdgcn_mfma_f32_16x16x32_bf16(af[fm], bf[fn], acc[fm][fn], 0, 0, 0);
      }
    }

    if (EPI == 4){
      #pragma unroll
      for (int fm = 0; fm < 4; fm++){
        const int mm_l = wr*64 + fm*16 + g*4;
        float bb[4];
        #pragma unroll
        for (int r = 0; r < 4; r++) bb[r] = bias[kc*512 + m0 + mm_l + r];
        #pragma unroll
        for (int fn = 0; fn < 4; fn++){
          float p = psh[kc*128 + wc*64 + fn*16 + col];
          #pragma unroll
          for (int r = 0; r < 4; r++)
            facc[fm][fn][r] += p * (acc[fm][fn][r] + bb[r]);
        }
      }
    }
  }

  // ---- LDS-staged epilogue ----
  __syncthreads();                       // all K-loop LDS reads done
  US* tile = shb;                        // 128 x 128 bf16, swizzled
  #pragma unroll
  for (int fm = 0; fm < 4; fm++){
    const int mm_l = wr*64 + fm*16 + g*4;
    float bb[4];
    if (EPI <= 3){
      #pragma unroll
      for (int r = 0; r < 4; r++) bb[r] = bias[m0 + mm_l + r];
    }
    #pragma unroll
    for (int fn = 0; fn < 4; fn++){
      const int nn_l = wc*64 + fn*16 + col;
      f32x4 v = (EPI == 4) ? facc[fm][fn] : acc[fm][fn];
      if (EPI == 5){
        #pragma unroll
        for (int r = 0; r < 4; r++){
          int row = mm_l + r;
          int byte = row*256 + ((nn_l*2) ^ ((row & 7) << 4));
          *(US*)((char*)tile + byte) = f2b(v[r]);
        }
      } else {
        US pk[4];
        #pragma unroll
        for (int r = 0; r < 4; r++){
          float val = v[r];
          if (EPI <= 3) val += bb[r];
          if (EPI == 1) val = 0.5f*val*(1.f + erff(val*0.70710678f));
          if (EPI == 2){ int m = m0 + mm_l + r; val = val*(s1v[m]*0.99999500f) + s2v[m]; val = val/(1.f + expf(-val)); }
          if (EPI == 3){ val = val/(1.f + expf(-val)); }
          pk[r] = f2b(val);
        }
        int byte = nn_l*256 + ((mm_l*2) ^ ((nn_l & 7) << 4));
        *(int2*)((char*)tile + byte) = *(int2*)pk;
      }
    }
  }
  __syncthreads();
  const int r0 = tid >> 4, c = tid & 15;
  #pragma unroll
  for (int p = 0; p < 8; p++){
    int r = p*16 + r0;
    int4 vv = *(const int4*)((const char*)tile + r*256 + ((c*16) ^ ((r & 7) << 4)));
    long obase = (EPI == 5) ? ((long)b*sOut + (long)(m0 + r)*ldo + n0)
                            : ((long)b*sOut + (long)(n0 + r)*ldo + moff + m0);
    *(int4*)((US*)Out + obase + c*8) = vv;
  }
}

// ---------------- small tail kernels ----------------
__global__ __launch_bounds__(256) void k_pool(const US* __restrict__ h2, float* __restrict__ feat){
  int b = blockIdx.x, c = threadIdx.x;
  float s = 0.f;
  for (int t = 0; t < SS; t++) s += b2sf(h2[((long)(b*SS + t))*HD + c]);
  feat[b*HD + c] = s * (1.f/SS);
}
__global__ void k_params(const float* __restrict__ feat, const float* __restrict__ pw,
                         const float* __restrict__ pb, float* __restrict__ dynA, float* __restrict__ dynB){
  int t = threadIdx.x;
  if (t >= 128) return;
  int b = t >> 3, j = t & 7;
  float s = pb[j];
  for (int c = 0; c < HD; c++) s += feat[b*HD + c]*pw[j*HD + c];
  int k = j >> 1;
  if ((j & 1) == 0){
    float sp = s > 20.f ? s : log1pf(expf(s));
    dynA[b*4 + k] = sp + 0.01f;
  } else {
    dynB[b*4 + k] = 1024.f/(1.f + expf(-s));
  }
}
// psi[b][k][s]
__global__ void k_psi(const float* __restrict__ dynA, const float* __restrict__ dynB, float* __restrict__ psi){
  int i = blockIdx.x*256 + threadIdx.x;
  if (i >= NB*4*SS) return;
  int b = i >> 12, k = (i >> 10) & 3, s = i & (SS-1);
  float u = ((float)s - dynB[b*4 + k]) / dynA[b*4 + k];
  psi[i] = 0.86732507f*(1.f - u*u)*expf(-0.5f*u*u);
}
// y = base + kan*2*sigmoid(gate) + x; LayerNorm over D
__global__ __launch_bounds__(128) void k_final(const US* __restrict__ base, const US* __restrict__ kan,
    const US* __restrict__ gate, const void* __restrict__ x,
    void* __restrict__ out, const float* __restrict__ lng, const float* __restrict__ lnb,
    const int* __restrict__ fl){
  int isf = fl[0];
  long row = blockIdx.x;               // b*S + s
  int t = threadIdx.x;
  long off = row*DD + t*4;
  ushort4 bs = *(const ushort4*)&base[off];
  ushort4 gt = *(const ushort4*)&gate[off];
  ushort4 kn = *(const ushort4*)&kan[off];
  float xv[4];
  if (isf){ float4 q = *(const float4*)((const float*)x + off); xv[0]=q.x; xv[1]=q.y; xv[2]=q.z; xv[3]=q.w; }
  else { ushort4 q = *(const ushort4*)((const US*)x + off); xv[0]=b2sf(q.x); xv[1]=b2sf(q.y); xv[2]=b2sf(q.z); xv[3]=b2sf(q.w); }
  float bv[4] = {b2sf(bs.x), b2sf(bs.y), b2sf(bs.z), b2sf(bs.w)};
  float gv[4] = {b2sf(gt.x), b2sf(gt.y), b2sf(gt.z), b2sf(gt.w)};
  const US* kp = (const US*)&kn;
  float y[4];
  float sm = 0.f, ssq = 0.f;
  #pragma unroll
  for (int r = 0; r < 4; r++){
    float amp = 2.f/(1.f + expf(-gv[r]));
    y[r] = bv[r] + b2sf(kp[r])*amp + xv[r];
    sm += y[r]; ssq += y[r]*y[r];
  }
  for (int o = 32; o; o >>= 1){ sm += __shfl_down(sm, o); ssq += __shfl_down(ssq, o); }
  __shared__ float sh[4];
  int lane = t & 63, wid = t >> 6;
  if (lane == 0){ sh[wid*2] = sm; sh[wid*2+1] = ssq; }
  __syncthreads();
  float S1 = sh[0] + sh[2], S2 = sh[1] + sh[3];
  float mean = S1*(1.f/DD), var = S2*(1.f/DD) - mean*mean;
  float rstd = rsqrtf(var + 1e-5f);
  #pragma unroll
  for (int r = 0; r < 4; r++){
    int d = t*4 + r;
    float val = (y[r] - mean)*rstd*lng[d] + lnb[d];
    if (isf) ((float*)out)[off + r] = val;
    else     ((US*)out)[off + r] = f2b(val);
  }
}

extern "C" void kernel_launch(void* const* d_in, const int* in_sizes, int n_in,
                              void* d_out, int out_size, void* d_ws, size_t ws_size,
                              hipStream_t stream){
  const void* x       = d_in[0];
  const void* conv_w  = d_in[1];
  const void* conv_b  = d_in[2];
  const void* fusion_w= d_in[3];
  const void* fusion_b= d_in[4];
  const void* refine_w= d_in[5];
  const void* refine_b= d_in[6];
  const void* hyp1_w  = d_in[7];
  const void* hyp1_b  = d_in[8];
  const void* bn_g    = d_in[9];
  const void* bn_b    = d_in[10];
  const void* hyp2_w  = d_in[11];
  const void* hyp2_b  = d_in[12];
  const void* proj_w  = d_in[13];
  const void* proj_b  = d_in[14];
  const void* gate_w  = d_in[15];
  const void* gate_b  = d_in[16];
  const void* base_w  = d_in[17];
  const void* base_b  = d_in[18];
  const void* wav_w   = d_in[19];
  const void* wav_b   = d_in[20];
  const void* ln_g    = d_in[21];
  const void* ln_b    = d_in[22];

  char* wsb = (char*)d_ws;
  long off = 0;
  auto AA = [&](long bytes)->char*{ char* p = wsb + off; off += (bytes + 255) & ~255L; return p; };
  US* padG  = (US*)AA((long)NB*SP*DD*2);   // pad buffer, later gate
  US* smA   = (US*)AA((long)NB*SS*DD*2);   // x_smooth ping
  US* smB   = (US*)AA((long)NB*SS*DD*2);   // x_smooth pong / spike
  US* xTh   = (US*)AA((long)NB*SS*DD*2);   // xT, later h1
  US* cc    = (US*)AA((long)NB*SS*2048*2); // concat / h2+siluS / kan
  US* baseB = (US*)AA((long)NB*SS*DD*2);
  US* Wc  = (US*)AA(4L*512*1536*2);        // [2048][1536]
  US* Wr  = (US*)AA(512L*1536*2);
  US* Wh1 = (US*)AA(512L*1536*2);
  US* Wh2 = (US*)AA(256L*1536*2);
  US* Wwv = (US*)AA(4L*512*512*2);         // [2048][512]
  US* Fw  = (US*)AA(512L*2048*2);
  US* BW  = (US*)AA(512L*512*2);
  US* GW  = (US*)AA(512L*512*2);
  US* Cm  = (US*)AA(1024L*1024*2);
  float* gvec = (float*)AA(1024*4);
  float* cb_f = (float*)AA(2048*4);
  float* fz_b = (float*)AA(512*4);
  float* rf_b = (float*)AA(512*4);
  float* h1_b = (float*)AA(512*4);
  float* h2_b = (float*)AA(256*4);
  float* bs_b = (float*)AA(512*4);
  float* gt_b = (float*)AA(512*4);
  float* wv_b = (float*)AA(2048*4);
  float* bngf = (float*)AA(512*4);
  float* bnbf = (float*)AA(512*4);
  float* pwf  = (float*)AA(2048*4);
  float* pbf  = (float*)AA(8*4);
  float* lngf = (float*)AA(512*4);
  float* lnbf = (float*)AA(512*4);
  float* feat = (float*)AA(16*256*4);
  float* dynA = (float*)AA(64*4);
  float* dynB = (float*)AA(64*4);
  float* psi  = (float*)AA((long)NB*4*SS*4);
  int* flag   = (int*)AA(64);
  if ((size_t)off > ws_size) return;
  US* h2    = cc;                 // [B,S,256]
  US* siluS = cc + 16777216;      // [B,S,D]
  US* kanb  = cc;                 // [B,S,D] (h2 dead by then; no overlap with siluS)

  auto g1 = [](long n){ return dim3((unsigned)((n + 255)/256)); };
  const long sAct = (long)SS*DD*2;     // batch stride bytes for [B,S,D]
  const long sPad = (long)SP*DD*2;
  const long sCC  = (long)SS*2048*2;
  const long oAct = (long)SS*DD;       // out batch stride, elements
  const long oCC  = (long)SS*2048;
  const long oH2  = (long)SS*HD;

  k_detect<<<1, 256, 0, stream>>>(x, flag);

  k_repack3<<<g1(2048L*512*3), 256, 0, stream>>>(conv_w, Wc, 2048, 512, flag);
  k_repack3<<<g1(512L*512*3), 256, 0, stream>>>(refine_w, Wr, 512, 512, flag);
  k_repack3<<<g1(512L*512*3), 256, 0, stream>>>(hyp1_w, Wh1, 512, 512, flag);
  k_repack3<<<g1(256L*512*3), 256, 0, stream>>>(hyp2_w, Wh2, 256, 512, flag);
  k_repack_wav<<<g1(4L*512*512), 256, 0, stream>>>(wav_w, Wwv, flag);
  k_cvt_b<<<g1(512L*2048), 256, 0, stream>>>(fusion_w, Fw, 512L*2048, flag);
  k_cvt_b<<<g1(512L*512), 256, 0, stream>>>(base_w, BW, 512L*512, flag);
  k_cvt_b<<<g1(512L*512), 256, 0, stream>>>(gate_w, GW, 512L*512, flag);
  k_cvt_f<<<g1(2048), 256, 0, stream>>>(conv_b, cb_f, 2048, flag);
  k_cvt_f<<<g1(512), 256, 0, stream>>>(fusion_b, fz_b, 512, flag);
  k_cvt_f<<<g1(512), 256, 0, stream>>>(refine_b, rf_b, 512, flag);
  k_cvt_f<<<g1(512), 256, 0, stream>>>(hyp1_b, h1_b, 512, flag);
  k_cvt_f<<<g1(256), 256, 0, stream>>>(hyp2_b, h2_b, 256, flag);
  k_cvt_f<<<g1(512), 256, 0, stream>>>(base_b, bs_b, 512, flag);
  k_cvt_f<<<g1(512), 256, 0, stream>>>(gate_b, gt_b, 512, flag);
  k_cvt_f<<<g1(2048), 256, 0, stream>>>(wav_b, wv_b, 2048, flag);
  k_cvt_f<<<g1(512), 256, 0, stream>>>(bn_g, bngf, 512, flag);
  k_cvt_f<<<g1(512), 256, 0, stream>>>(bn_b, bnbf, 512, flag);
  k_cvt_f<<<g1(2048), 256, 0, stream>>>(proj_w, pwf, 2048, flag);
  k_cvt_f<<<g1(8), 256, 0, stream>>>(proj_b, pbf, 8, flag);
  k_cvt_f<<<g1(512), 256, 0, stream>>>(ln_g, lngf, 512, flag);
  k_cvt_f<<<g1(512), 256, 0, stream>>>(ln_b, lnbf, 512, flag);
  k_build_g<<<g1(SS), 256, 0, stream>>>(gvec);
  k_build_cmat<<<g1((long)SS*SS), 256, 0, stream>>>(gvec, Cm);
  k_transpose_b<<<dim3(SS/32, DD/32, NB), 256, 0, stream>>>(x, xTh, flag);

  // ---- circulant low-pass: smA[b][s][d] = sum_s' Cm[s][s'] * xT[b][d][s'] ----
  k_mfma<5,false><<<dim3(4*NB, 8), 256, 0, stream>>>(Cm, xTh, smA,
      4, 1024, (long)DD*SS*2, SS*2, 0, oAct, DD, 0, nullptr, nullptr, nullptr, nullptr);

  // ---- 2 iterations: merged 4-dilation conv (K=1536, gelu) -> fusion ----
  US* cur = smA; US* nxt = smB;
  for (int it = 0; it < 2; ++it){
    k_pad_b<<<g1((long)NB*SP*128), 256, 0, stream>>>(cur, nullptr, padG, flag);
    k_mfma<1,true><<<dim3(8*NB, 16), 256, 0, stream>>>(Wc, padG, cc,
        8, 1536, sPad, DD*2, -1, oCC, 2048, 0, cb_f, nullptr, nullptr, nullptr);
    k_mfma<0,false><<<dim3(8*NB, 4), 256, 0, stream>>>(Fw, cc, nxt,
        8, 2048, sCC, 4096, 0, oAct, DD, 0, fz_b, nullptr, nullptr, nullptr);
    US* t = cur; cur = nxt; nxt = t;   // after 2 iters: cur == smA
  }

  // ---- spike = refine(x - x_smooth) ----
  k_pad_b<<<g1((long)NB*SP*128), 256, 0, stream>>>(cur, x, padG, flag);
  k_mfma<0,true><<<dim3(8*NB, 4), 256, 0, stream>>>(Wr, padG, smB,
      8, 1536, sPad, DD*2, 1, oAct, DD, 0, rf_b, nullptr, nullptr, nullptr);

  // ---- hypernet ----
  k_pad_b<<<g1((long)NB*SP*128), 256, 0, stream>>>(cur, nullptr, padG, flag);
  k_mfma<2,true><<<dim3(8*NB, 4), 256, 0, stream>>>(Wh1, padG, xTh,
      8, 1536, sPad, DD*2, 1, oAct, DD, 0, h1_b, bngf, bnbf, nullptr);
  k_pad_b<<<g1((long)NB*SP*128), 256, 0, stream>>>(xTh, nullptr, padG, flag);
  k_mfma<3,true><<<dim3(8*NB, 2), 256, 0, stream>>>(Wh2, padG, h2,
      8, 1536, sPad, DD*2, 1, oH2, HD, 0, h2_b, nullptr, nullptr, nullptr);
  k_pool<<<NB, 256, 0, stream>>>(h2, feat);
  k_params<<<1, 128, 0, stream>>>(feat, pwf, pbf, dynA, dynB);
  k_psi<<<g1(NB*4*SS), 256, 0, stream>>>(dynA, dynB, psi);

  // ---- base / gate ----
  k_silu_b<<<g1((long)NB*SS*DD/4), 256, 0, stream>>>(cur, siluS);
  k_mfma<0,false><<<dim3(8*NB, 4), 256, 0, stream>>>(BW, siluS, baseB,
      8, 512, sAct, DD*2, 0, oAct, DD, 0, bs_b, nullptr, nullptr, nullptr);
  k_mfma<0,false><<<dim3(8*NB, 4), 256, 0, stream>>>(GW, baseB, padG,
      8, 512, sAct, DD*2, 0, oAct, DD, 0, gt_b, nullptr, nullptr, nullptr);

  // ---- psi-fused wavelet: kan[b][s][e] = sum_k psi_k[s]*(spike @ Wwv_k^T + wav_b_k) ----
  k_mfma<4,false><<<dim3(8*NB, 4), 256, 0, stream>>>(Wwv, smB, kanb,
      8, 512, sAct, DD*2, 0, oAct, DD, 0, wv_b, nullptr, nullptr, psi);

  // ---- combine + residual + LayerNorm ----
  k_final<<<NB*SS, 128, 0, stream>>>(baseB, kanb, padG, x, d_out, lngf, lnbf, flag);
}

// Round 6
// 680.422 us; speedup vs baseline: 8.7325x; 1.1276x over previous
//
#include <hip/hip_runtime.h>
#include <hip/hip_bf16.h>
#include <math.h>

#define NB 16
#define SS 1024
#define DD 512
#define HD 256

typedef unsigned short US;
typedef short bf16x8 __attribute__((ext_vector_type(8)));
typedef float f32x4 __attribute__((ext_vector_type(4)));
typedef __attribute__((address_space(1))) const void gv1;
typedef __attribute__((address_space(3))) void lv3;

static __device__ __forceinline__ float b2sf(US u){ return __uint_as_float(((unsigned)u)<<16); }
static __device__ __forceinline__ US f2b(float f){
  __hip_bfloat16 h = __float2bfloat16(f);
  union { __hip_bfloat16 h; US u; } c; c.h = h; return c.u;
}
static __device__ __forceinline__ float rd(const void* __restrict__ p, long i, int isf){
  return isf ? ((const float*)p)[i] : b2sf(((const US*)p)[i]);
}

// ---------------- dtype detection ----------------
__global__ void k_detect(const void* __restrict__ x, int* __restrict__ flag){
  const US* u = (const US*)x;
  int t = threadIdx.x;
  float m = 0.f;
  for (int i = t; i < 4096; i += 256){
    float v = fabsf(b2sf(u[i]));
    if (isnan(v) || isinf(v)) v = 1e30f;
    m = fmaxf(m, v);
  }
  for (int off = 32; off; off >>= 1) m = fmaxf(m, __shfl_down(m, off));
  __shared__ float sh[4];
  if ((t & 63) == 0) sh[t >> 6] = m;
  __syncthreads();
  if (t == 0){
    float mm = fmaxf(fmaxf(sh[0], sh[1]), fmaxf(sh[2], sh[3]));
    flag[0] = (mm > 1e6f) ? 1 : 0;
  }
}

// ---------------- merged weight prep (8 segments -> 1 contiguous bf16 block) ----------------
// type 0: [O][C][3] -> [O][3*C]   (conv/refine/hyp1/hyp2)
// type 1: wav [4][d][e] -> [4][e][d]
// type 2: plain convert
struct WTab { const void* src[8]; long start[9]; int type[8]; int C[8]; };
__global__ void k_prep_w(WTab wt, US* __restrict__ dst, const int* __restrict__ fl){
  int isf = fl[0];
  long i = (long)blockIdx.x*256 + threadIdx.x;
  if (i >= wt.start[8]) return;
  int s = 0;
  while (i >= wt.start[s+1]) s++;
  long r = i - wt.start[s];
  long si;
  if (wt.type[s] == 0){
    int C = wt.C[s]; long oc3 = 3L*C;
    int o = (int)(r / oc3); int rr = (int)(r - (long)o*oc3); int t = rr / C; int c = rr - t*C;
    si = ((long)o*C + c)*3 + t;
  } else if (wt.type[s] == 1){
    int k = (int)(r >> 18); int e = (int)((r >> 9) & 511); int d = (int)(r & 511);
    si = ((long)(k*512 + d))*512 + e;
  } else si = r;
  dst[i] = f2b(rd(wt.src[s], si, isf));
}

// ---------------- merged f32 converts (14 segments -> 1 contiguous f32 block) ----------------
struct FTab { const void* src[14]; int start[15]; };
__global__ void k_cvt_all(FTab ft, float* __restrict__ dst, const int* __restrict__ fl){
  int isf = fl[0];
  int i = blockIdx.x*256 + threadIdx.x;
  if (i >= ft.start[14]) return;
  int s = 0;
  while (i >= ft.start[s+1]) s++;
  dst[i] = rd(ft.src[s], i - ft.start[s], isf);
}

// Dirichlet low-pass kernel
__global__ void k_build_g(float* __restrict__ g){
  int d = blockIdx.x*256 + threadIdx.x;
  if (d >= SS) return;
  float s = 1.f;
  for (int k = 1; k < 102; ++k){
    int r = (k*d) & (SS-1);
    s += 2.f * cosf(6.28318530718f * (float)r * (1.f/SS));
  }
  g[d] = s * (1.f/SS);
}
__global__ void k_build_cmat(const float* __restrict__ g, US* __restrict__ cm){
  int i = blockIdx.x*256 + threadIdx.x;
  if (i >= SS*SS) return;
  int t = i >> 10, s = i & (SS-1);
  cm[i] = f2b(g[(s - t) & (SS-1)]);
}
// x [B,S,D] -> xT [B,D,S] bf16
__global__ __launch_bounds__(256) void k_transpose_b(const void* __restrict__ x, US* __restrict__ xt, const int* __restrict__ fl){
  int isf = fl[0];
  __shared__ float tl[32][33];
  int b = blockIdx.z, s0 = blockIdx.x*32, d0 = blockIdx.y*32;
  int tx = threadIdx.x & 31, ty = threadIdx.x >> 5;
  for (int i = ty; i < 32; i += 8)
    tl[i][tx] = rd(x, ((long)(b*SS + s0+i))*DD + d0+tx, isf);
  __syncthreads();
  for (int i = ty; i < 32; i += 8)
    xt[((long)(b*DD + d0+i))*SS + s0+tx] = f2b(tl[tx][i]);
}
// diff = x - smooth (refine input); sils = silu(smooth) (base input)
__global__ void k_diff_silu(const US* __restrict__ sm, const void* __restrict__ x,
                            US* __restrict__ diff, US* __restrict__ sils, const int* __restrict__ fl){
  int isf = fl[0];
  long i = (long)blockIdx.x*256 + threadIdx.x;
  if (i >= (long)NB*SS*DD/4) return;
  ushort4 s4 = *(const ushort4*)&sm[i*4];
  float sv[4] = {b2sf(s4.x), b2sf(s4.y), b2sf(s4.z), b2sf(s4.w)};
  float xv[4];
  if (isf){ float4 q = *(const float4*)((const float*)x + i*4); xv[0]=q.x; xv[1]=q.y; xv[2]=q.z; xv[3]=q.w; }
  else { ushort4 q = *(const ushort4*)((const US*)x + i*4); xv[0]=b2sf(q.x); xv[1]=b2sf(q.y); xv[2]=b2sf(q.z); xv[3]=b2sf(q.w); }
  ushort4 d4, l4;
  US* dp = (US*)&d4; US* lp = (US*)&l4;
  #pragma unroll
  for (int r = 0; r < 4; r++){
    dp[r] = f2b(xv[r] - sv[r]);
    lp[r] = f2b(sv[r]/(1.f + expf(-sv[r])));
  }
  *(ushort4*)&diff[i*4] = d4;
  *(ushort4*)&sils[i*4] = l4;
}

// ---------------- MFMA GEMM ----------------
// C[m][n] = sum_k A[m][k] * Bt[n][k], batched.
// Grid: blockIdx.x = ny + NYB*b (B-panel id; same panel -> same XCD),
//       blockIdx.y = mx (panel-sharing axis; linear stride NYB*NB % 8 == 0).
// TAPPED: B-row = clamp(n + (tap-1)*dil) into an unpadded [S] row index (edge conv);
//         dil < 0 => per-m-tile dilation 1<<(m0>>9) (merged 4-dilation conv).
// EPI: 0=bias, store bf16 out[b][n][m]; 1=+gelu; 2=+bn+silu; 3=+silu;
//      4=wavelet-fused: 4 K-chunks, facc += psi_k[n]*(acc+bias_k[m]);
//      5=NT store bf16 out[b][m][n], no bias.
// All stores go through an LDS-staged tile -> 16B coalesced global stores.
template<int EPI, bool TAPPED>
__global__ __launch_bounds__(256) void k_mfma(
    const US* __restrict__ A, const US* __restrict__ Bact, void* __restrict__ Out,
    int NYB, int K, long sBbytes, int ldbB, int dil,
    long sOut, int ldo,
    const float* __restrict__ bias, const float* __restrict__ s1v, const float* __restrict__ s2v,
    const float* __restrict__ psiP)
{
  __shared__ alignas(16) US shb[2*128*64];   // As | Bs, reused as 32KB out-tile
  __shared__ float psh[(EPI==4) ? 512 : 4];
  US* As = shb;
  US* Bs = shb + 128*64;
  const int bx = blockIdx.x;
  const int ny = bx % NYB;
  const int b  = bx / NYB;
  const int m0 = blockIdx.y*128, n0 = ny*128;
  const int dd = (TAPPED && dil < 0) ? (1 << (m0 >> 9)) : dil;
  const char* Bb = (const char*)Bact + (long)b*sBbytes;
  const int tid = threadIdx.x;
  const int lane = tid & 63, w = tid >> 6;
  const int wr = w >> 1, wc = w & 1;
  const int col = lane & 15, g = lane >> 4;

  if (EPI == 4){
    for (int i = tid; i < 512; i += 256)
      psh[i] = psiP[(long)b*4096 + (i >> 7)*SS + n0 + (i & 127)];
  }

  f32x4 acc[4][4];
  f32x4 facc[4][4];
  if (EPI == 4){
    #pragma unroll
    for (int i = 0; i < 4; i++)
      #pragma unroll
      for (int j = 0; j < 4; j++) facc[i][j] = (f32x4){0.f,0.f,0.f,0.f};
  }

  int rows_[4], sls_[4];
  #pragma unroll
  for (int i = 0; i < 4; i++){
    int c = w*256 + i*64 + lane;
    rows_[i] = c >> 3;
    sls_[i] = (c & 7) ^ ((c >> 3) & 7);
  }

  const int NKC = (EPI == 4) ? 4 : 1;
  for (int kc = 0; kc < NKC; ++kc){
    #pragma unroll
    for (int i = 0; i < 4; i++)
      #pragma unroll
      for (int j = 0; j < 4; j++) acc[i][j] = (f32x4){0.f,0.f,0.f,0.f};

    for (int k0 = 0; k0 < K; k0 += 64){
      const int c0 = TAPPED ? (k0 & 511) : k0;
      const int tapoff = TAPPED ? (((k0 >> 9) - 1)*dd) : 0;
      __syncthreads();   // previous iter's LDS reads done
      #pragma unroll
      for (int i = 0; i < 4; i++){
        const long arow = (long)(m0 + rows_[i]) + (EPI==4 ? kc*512 : 0);
        const char* ga = (const char*)A + (arow*K + k0)*2 + sls_[i]*16;
        __builtin_amdgcn_global_load_lds((gv1*)ga, (lv3*)&As[(w*256 + i*64)*8], 16, 0, 0);
        int brow = n0 + rows_[i] + tapoff;
        if (TAPPED) brow = brow < 0 ? 0 : (brow > SS-1 ? SS-1 : brow);
        const char* gb = Bb + (long)brow*ldbB + c0*2 + sls_[i]*16;
        __builtin_amdgcn_global_load_lds((gv1*)gb, (lv3*)&Bs[(w*256 + i*64)*8], 16, 0, 0);
      }
      __syncthreads();   // vmcnt(0) drained by compiler before barrier
      #pragma unroll
      for (int kk = 0; kk < 2; kk++){
        bf16x8 af[4], bf[4];
        #pragma unroll
        for (int f = 0; f < 4; f++){
          int rowa = wr*64 + f*16 + col;
          int sla = (g + kk*4) ^ (rowa & 7);
          af[f] = *(const bf16x8*)&As[rowa*64 + sla*8];
          int rowb = wc*64 + f*16 + col;
          int slb = (g + kk*4) ^ (rowb & 7);
          bf[f] = *(const bf16x8*)&Bs[rowb*64 + slb*8];
        }
        #pragma unroll
        for (int fm = 0; fm < 4; fm++)
          #pragma unroll
          for (int fn = 0; fn < 4; fn++)
            acc[fm][fn] = __builtin_amdgcn_mfma_f32_16x16x32_bf16(af[fm], bf[fn], acc[fm][fn], 0, 0, 0);
      }
    }

    if (EPI == 4){
      #pragma unroll
      for (int fm = 0; fm < 4; fm++){
        const int mm_l = wr*64 + fm*16 + g*4;
        float bb[4];
        #pragma unroll
        for (int r = 0; r < 4; r++) bb[r] = bias[kc*512 + m0 + mm_l + r];
        #pragma unroll
        for (int fn = 0; fn < 4; fn++){
          float p = psh[kc*128 + wc*64 + fn*16 + col];
          #pragma unroll
          for (int r = 0; r < 4; r++)
            facc[fm][fn][r] += p * (acc[fm][fn][r] + bb[r]);
        }
      }
    }
  }

  // ---- LDS-staged epilogue ----
  __syncthreads();                       // all K-loop LDS reads done
  US* tile = shb;                        // 128 x 128 bf16, swizzled
  #pragma unroll
  for (int fm = 0; fm < 4; fm++){
    const int mm_l = wr*64 + fm*16 + g*4;
    float bb[4];
    if (EPI <= 3){
      #pragma unroll
      for (int r = 0; r < 4; r++) bb[r] = bias[m0 + mm_l + r];
    }
    #pragma unroll
    for (int fn = 0; fn < 4; fn++){
      const int nn_l = wc*64 + fn*16 + col;
      f32x4 v = (EPI == 4) ? facc[fm][fn] : acc[fm][fn];
      if (EPI == 5){
        #pragma unroll
        for (int r = 0; r < 4; r++){
          int row = mm_l + r;
          int byte = row*256 + ((nn_l*2) ^ ((row & 7) << 4));
          *(US*)((char*)tile + byte) = f2b(v[r]);
        }
      } else {
        US pk[4];
        #pragma unroll
        for (int r = 0; r < 4; r++){
          float val = v[r];
          if (EPI <= 3) val += bb[r];
          if (EPI == 1) val = 0.5f*val*(1.f + erff(val*0.70710678f));
          if (EPI == 2){ int m = m0 + mm_l + r; val = val*(s1v[m]*0.99999500f) + s2v[m]; val = val/(1.f + expf(-val)); }
          if (EPI == 3){ val = val/(1.f + expf(-val)); }
          pk[r] = f2b(val);
        }
        int byte = nn_l*256 + ((mm_l*2) ^ ((nn_l & 7) << 4));
        *(int2*)((char*)tile + byte) = *(int2*)pk;
      }
    }
  }
  __syncthreads();
  const int r0 = tid >> 4, c = tid & 15;
  #pragma unroll
  for (int p = 0; p < 8; p++){
    int r = p*16 + r0;
    int4 vv = *(const int4*)((const char*)tile + r*256 + ((c*16) ^ ((r & 7) << 4)));
    long obase = (EPI == 5) ? ((long)b*sOut + (long)(m0 + r)*ldo + n0)
                            : ((long)b*sOut + (long)(n0 + r)*ldo + m0);
    *(int4*)((US*)Out + obase + c*8) = vv;
  }
}

// ---------------- small tail kernels ----------------
// stage 1: partial sums over 128-row chunks
__global__ __launch_bounds__(256) void k_pool1(const US* __restrict__ h2, float* __restrict__ part){
  int blk = blockIdx.x;          // b*8 + chunk
  int b = blk >> 3, ch = blk & 7;
  int c = threadIdx.x;
  float s = 0.f;
  for (int t = ch*128; t < ch*128 + 128; t++) s += b2sf(h2[((long)(b*SS + t))*HD + c]);
  part[(blk << 8) | c] = s;
}
__global__ __launch_bounds__(256) void k_pool2(const float* __restrict__ part, float* __restrict__ feat){
  int b = blockIdx.x, c = threadIdx.x;
  float s = 0.f;
  for (int ch = 0; ch < 8; ch++) s += part[((b*8 + ch) << 8) | c];
  feat[b*HD + c] = s * (1.f/SS);
}
__global__ void k_params(const float* __restrict__ feat, const float* __restrict__ pw,
                         const float* __restrict__ pb, float* __restrict__ dynA, float* __restrict__ dynB){
  int t = threadIdx.x;
  if (t >= 128) return;
  int b = t >> 3, j = t & 7;
  float s = pb[j];
  for (int c = 0; c < HD; c++) s += feat[b*HD + c]*pw[j*HD + c];
  int k = j >> 1;
  if ((j & 1) == 0){
    float sp = s > 20.f ? s : log1pf(expf(s));
    dynA[b*4 + k] = sp + 0.01f;
  } else {
    dynB[b*4 + k] = 1024.f/(1.f + expf(-s));
  }
}
// psi[b][k][s]
__global__ void k_psi(const float* __restrict__ dynA, const float* __restrict__ dynB, float* __restrict__ psi){
  int i = blockIdx.x*256 + threadIdx.x;
  if (i >= NB*4*SS) return;
  int b = i >> 12, k = (i >> 10) & 3, s = i & (SS-1);
  float u = ((float)s - dynB[b*4 + k]) / dynA[b*4 + k];
  psi[i] = 0.86732507f*(1.f - u*u)*expf(-0.5f*u*u);
}
// y = base + kan*2*sigmoid(gate) + x; LayerNorm over D
__global__ __launch_bounds__(128) void k_final(const US* __restrict__ base, const US* __restrict__ kan,
    const US* __restrict__ gate, const void* __restrict__ x,
    void* __restrict__ out, const float* __restrict__ lng, const float* __restrict__ lnb,
    const int* __restrict__ fl){
  int isf = fl[0];
  long row = blockIdx.x;               // b*S + s
  int t = threadIdx.x;
  long off = row*DD + t*4;
  ushort4 bs = *(const ushort4*)&base[off];
  ushort4 gt = *(const ushort4*)&gate[off];
  ushort4 kn = *(const ushort4*)&kan[off];
  float xv[4];
  if (isf){ float4 q = *(const float4*)((const float*)x + off); xv[0]=q.x; xv[1]=q.y; xv[2]=q.z; xv[3]=q.w; }
  else { ushort4 q = *(const ushort4*)((const US*)x + off); xv[0]=b2sf(q.x); xv[1]=b2sf(q.y); xv[2]=b2sf(q.z); xv[3]=b2sf(q.w); }
  float bv[4] = {b2sf(bs.x), b2sf(bs.y), b2sf(bs.z), b2sf(bs.w)};
  float gv[4] = {b2sf(gt.x), b2sf(gt.y), b2sf(gt.z), b2sf(gt.w)};
  const US* kp = (const US*)&kn;
  float y[4];
  float sm = 0.f, ssq = 0.f;
  #pragma unroll
  for (int r = 0; r < 4; r++){
    float amp = 2.f/(1.f + expf(-gv[r]));
    y[r] = bv[r] + b2sf(kp[r])*amp + xv[r];
    sm += y[r]; ssq += y[r]*y[r];
  }
  for (int o = 32; o; o >>= 1){ sm += __shfl_down(sm, o); ssq += __shfl_down(ssq, o); }
  __shared__ float sh[4];
  int lane = t & 63, wid = t >> 6;
  if (lane == 0){ sh[wid*2] = sm; sh[wid*2+1] = ssq; }
  __syncthreads();
  float S1 = sh[0] + sh[2], S2 = sh[1] + sh[3];
  float mean = S1*(1.f/DD), var = S2*(1.f/DD) - mean*mean;
  float rstd = rsqrtf(var + 1e-5f);
  #pragma unroll
  for (int r = 0; r < 4; r++){
    int d = t*4 + r;
    float val = (y[r] - mean)*rstd*lng[d] + lnb[d];
    if (isf) ((float*)out)[off + r] = val;
    else     ((US*)out)[off + r] = f2b(val);
  }
}

extern "C" void kernel_launch(void* const* d_in, const int* in_sizes, int n_in,
                              void* d_out, int out_size, void* d_ws, size_t ws_size,
                              hipStream_t stream){
  const void* x       = d_in[0];
  const void* conv_w  = d_in[1];
  const void* conv_b  = d_in[2];
  const void* fusion_w= d_in[3];
  const void* fusion_b= d_in[4];
  const void* refine_w= d_in[5];
  const void* refine_b= d_in[6];
  const void* hyp1_w  = d_in[7];
  const void* hyp1_b  = d_in[8];
  const void* bn_g    = d_in[9];
  const void* bn_b    = d_in[10];
  const void* hyp2_w  = d_in[11];
  const void* hyp2_b  = d_in[12];
  const void* proj_w  = d_in[13];
  const void* proj_b  = d_in[14];
  const void* gate_w  = d_in[15];
  const void* gate_b  = d_in[16];
  const void* base_w  = d_in[17];
  const void* base_b  = d_in[18];
  const void* wav_w   = d_in[19];
  const void* wav_b   = d_in[20];
  const void* ln_g    = d_in[21];
  const void* ln_b    = d_in[22];

  char* wsb = (char*)d_ws;
  long off = 0;
  auto AA = [&](long bytes)->char*{ char* p = wsb + off; off += (bytes + 255) & ~255L; return p; };
  US* smA   = (US*)AA((long)NB*SS*DD*2);   // x_smooth ping
  US* smB   = (US*)AA((long)NB*SS*DD*2);   // x_smooth pong / spike
  US* xTh   = (US*)AA((long)NB*SS*DD*2);   // xT -> h1 -> gate
  US* cc    = (US*)AA((long)NB*SS*2048*2); // concat / diff+h2+kan+siluS
  US* baseB = (US*)AA((long)NB*SS*DD*2);
  US* WBLK  = (US*)AA(7733248L*2);         // all bf16 weights contiguous
  US* Cm    = (US*)AA(1024L*1024*2);
  float* gvec = (float*)AA(1024*4);
  float* FBLK = (float*)AA(11016L*4);      // all f32 vectors contiguous
  float* feat = (float*)AA(16*256*4);
  float* part = (float*)AA(16*8*256*4);
  float* dynA = (float*)AA(64*4);
  float* dynB = (float*)AA(64*4);
  float* psi  = (float*)AA((long)NB*4*SS*4);
  int* flag   = (int*)AA(64);
  if ((size_t)off > ws_size) return;

  // weight block layout
  US* Wc  = WBLK;                 // [2048][1536]
  US* Wr  = Wc  + 3145728L;       // [512][1536]
  US* Wh1 = Wr  + 786432L;
  US* Wh2 = Wh1 + 786432L;        // [256][1536]
  US* Wwv = Wh2 + 393216L;        // [2048][512]
  US* Fw  = Wwv + 1048576L;       // [512][2048]
  US* BW  = Fw  + 1048576L;       // [512][512]
  US* GW  = BW  + 262144L;        // [512][512]
  // f32 block layout
  float* cb_f = FBLK;             // 2048
  float* fz_b = cb_f + 2048;      // 512
  float* rf_b = fz_b + 512;
  float* h1_b = rf_b + 512;
  float* h2_b = h1_b + 512;       // 256
  float* bs_b = h2_b + 256;       // 512
  float* gt_b = bs_b + 512;
  float* wv_b = gt_b + 512;       // 2048
  float* bngf = wv_b + 2048;      // 512
  float* bnbf = bngf + 512;
  float* pwf  = bnbf + 512;       // 2048
  float* pbf  = pwf  + 2048;      // 8
  float* lngf = pbf  + 8;         // 512
  float* lnbf = lngf + 512;
  // cc sub-buffers (time-disjoint)
  US* diff  = cc;                  // [B,S,D]   (after fusion it2, until refine)
  US* h2b   = cc;                  // [B,S,256] (after refine/hyp2)
  US* kanb  = cc + 8388608L;       // [B,S,D]
  US* siluS = cc + 16777216L;      // [B,S,D]

  auto g1 = [](long n){ return dim3((unsigned)((n + 255)/256)); };
  const long sAct = (long)SS*DD*2;     // batch stride bytes for [B,S,D]
  const long sCC  = (long)SS*2048*2;
  const long oAct = (long)SS*DD;       // out batch stride, elements
  const long oCC  = (long)SS*2048;
  const long oH2  = (long)SS*HD;

  k_detect<<<1, 256, 0, stream>>>(x, flag);

  { // merged weight prep
    WTab wt;
    const void* srcs[8] = {conv_w, refine_w, hyp1_w, hyp2_w, wav_w, fusion_w, base_w, gate_w};
    long sizes[8] = {3145728, 786432, 786432, 393216, 1048576, 1048576, 262144, 262144};
    int types[8] = {0,0,0,0,1,2,2,2};
    int Cs[8]    = {512,512,512,512,0,0,0,0};
    long acc_ = 0;
    for (int i = 0; i < 8; i++){ wt.src[i]=srcs[i]; wt.start[i]=acc_; wt.type[i]=types[i]; wt.C[i]=Cs[i]; acc_ += sizes[i]; }
    wt.start[8] = acc_;
    k_prep_w<<<g1(acc_), 256, 0, stream>>>(wt, WBLK, flag);
  }
  { // merged f32 converts
    FTab ft;
    const void* srcs[14] = {conv_b, fusion_b, refine_b, hyp1_b, hyp2_b, base_b, gate_b,
                            wav_b, bn_g, bn_b, proj_w, proj_b, ln_g, ln_b};
    int sizes[14] = {2048,512,512,512,256,512,512,2048,512,512,2048,8,512,512};
    int acc_ = 0;
    for (int i = 0; i < 14; i++){ ft.src[i]=srcs[i]; ft.start[i]=acc_; acc_ += sizes[i]; }
    ft.start[14] = acc_;
    k_cvt_all<<<g1(acc_), 256, 0, stream>>>(ft, FBLK, flag);
  }
  k_build_g<<<g1(SS), 256, 0, stream>>>(gvec);
  k_build_cmat<<<g1((long)SS*SS), 256, 0, stream>>>(gvec, Cm);
  k_transpose_b<<<dim3(SS/32, DD/32, NB), 256, 0, stream>>>(x, xTh, flag);

  // ---- circulant low-pass: smA[b][s][d] = sum_s' Cm[s][s'] * xT[b][d][s'] ----
  k_mfma<5,false><<<dim3(4*NB, 8), 256, 0, stream>>>(Cm, xTh, smA,
      4, 1024, (long)DD*SS*2, SS*2, 0, oAct, DD, nullptr, nullptr, nullptr, nullptr);

  // ---- 2 iterations: merged 4-dilation conv (K=1536, clamped taps, gelu) -> fusion ----
  US* cur = smA; US* nxt = smB;
  for (int it = 0; it < 2; ++it){
    k_mfma<1,true><<<dim3(8*NB, 16), 256, 0, stream>>>(Wc, cur, cc,
        8, 1536, sAct, DD*2, -1, oCC, 2048, cb_f, nullptr, nullptr, nullptr);
    k_mfma<0,false><<<dim3(8*NB, 4), 256, 0, stream>>>(Fw, cc, nxt,
        8, 2048, sCC, 4096, 0, oAct, DD, fz_b, nullptr, nullptr, nullptr);
    US* t = cur; cur = nxt; nxt = t;   // after 2 iters: cur == smA
  }

  // ---- diff = x - smooth ; siluS = silu(smooth) ----
  k_diff_silu<<<g1((long)NB*SS*DD/4), 256, 0, stream>>>(cur, x, diff, siluS, flag);

  // ---- spike = refine(diff) ----
  k_mfma<0,true><<<dim3(8*NB, 4), 256, 0, stream>>>(Wr, diff, smB,
      8, 1536, sAct, DD*2, 1, oAct, DD, rf_b, nullptr, nullptr, nullptr);

  // ---- hypernet ----
  k_mfma<2,true><<<dim3(8*NB, 4), 256, 0, stream>>>(Wh1, cur, xTh,
      8, 1536, sAct, DD*2, 1, oAct, DD, h1_b, bngf, bnbf, nullptr);
  k_mfma<3,true><<<dim3(8*NB, 2), 256, 0, stream>>>(Wh2, xTh, h2b,
      8, 1536, sAct, DD*2, 1, oH2, HD, h2_b, nullptr, nullptr, nullptr);
  k_pool1<<<NB*8, 256, 0, stream>>>(h2b, part);
  k_pool2<<<NB, 256, 0, stream>>>(part, feat);
  k_params<<<1, 128, 0, stream>>>(feat, pwf, pbf, dynA, dynB);
  k_psi<<<g1(NB*4*SS), 256, 0, stream>>>(dynA, dynB, psi);

  // ---- base / gate ----
  k_mfma<0,false><<<dim3(8*NB, 4), 256, 0, stream>>>(BW, siluS, baseB,
      8, 512, sAct, DD*2, 0, oAct, DD, bs_b, nullptr, nullptr, nullptr);
  k_mfma<0,false><<<dim3(8*NB, 4), 256, 0, stream>>>(GW, baseB, xTh,
      8, 512, sAct, DD*2, 0, oAct, DD, gt_b, nullptr, nullptr, nullptr);

  // ---- psi-fused wavelet: kan[b][s][e] = sum_k psi_k[s]*(spike @ Wwv_k^T + wav_b_k) ----
  k_mfma<4,false><<<dim3(8*NB, 4), 256, 0, stream>>>(Wwv, smB, kanb,
      8, 512, sAct, DD*2, 0, oAct, DD, wv_b, nullptr, nullptr, psi);

  // ---- combine + residual + LayerNorm ----
  k_final<<<NB*SS, 128, 0, stream>>>(baseB, kanb, xTh, x, d_out, lngf, lnbf, flag);
}

// Round 8
// 671.158 us; speedup vs baseline: 8.8530x; 1.0138x over previous
//
#include <hip/hip_runtime.h>
#include <hip/hip_bf16.h>
#include <math.h>

#define NB 16
#define SS 1024
#define DD 512
#define HD 256

typedef unsigned short US;
typedef short bf16x8 __attribute__((ext_vector_type(8)));
typedef float f32x4 __attribute__((ext_vector_type(4)));
typedef __attribute__((address_space(1))) const void gv1;
typedef __attribute__((address_space(3))) void lv3;

static __device__ __forceinline__ float b2sf(US u){ return __uint_as_float(((unsigned)u)<<16); }
static __device__ __forceinline__ US f2b(float f){
  __hip_bfloat16 h = __float2bfloat16(f);
  union { __hip_bfloat16 h; US u; } c; c.h = h; return c.u;
}
static __device__ __forceinline__ float rd(const void* __restrict__ p, long i, int isf){
  return isf ? ((const float*)p)[i] : b2sf(((const US*)p)[i]);
}

__global__ void k_detect(const void* __restrict__ x, int* __restrict__ flag){
  const US* u = (const US*)x;
  int t = threadIdx.x;
  float m = 0.f;
  for (int i = t; i < 4096; i += 256){
    float v = fabsf(b2sf(u[i]));
    if (isnan(v) || isinf(v)) v = 1e30f;
    m = fmaxf(m, v);
  }
  for (int off = 32; off; off >>= 1) m = fmaxf(m, __shfl_down(m, off));
  __shared__ float sh[4];
  if ((t & 63) == 0) sh[t >> 6] = m;
  __syncthreads();
  if (t == 0){
    float mm = fmaxf(fmaxf(sh[0], sh[1]), fmaxf(sh[2], sh[3]));
    flag[0] = (mm > 1e6f) ? 1 : 0;
  }
}

struct WTab { const void* src[8]; long start[9]; int type[8]; int C[8]; };
__global__ void k_prep_w(WTab wt, US* __restrict__ dst, const int* __restrict__ fl){
  int isf = fl[0];
  long i = (long)blockIdx.x*256 + threadIdx.x;
  if (i >= wt.start[8]) return;
  int s = 0;
  while (i >= wt.start[s+1]) s++;
  long r = i - wt.start[s];
  long si;
  if (wt.type[s] == 0){
    int C = wt.C[s]; long oc3 = 3L*C;
    int o = (int)(r / oc3); int rr = (int)(r - (long)o*oc3); int t = rr / C; int c = rr - t*C;
    si = ((long)o*C + c)*3 + t;
  } else if (wt.type[s] == 1){
    int k = (int)(r >> 18); int e = (int)((r >> 9) & 511); int d = (int)(r & 511);
    si = ((long)(k*512 + d))*512 + e;
  } else si = r;
  dst[i] = f2b(rd(wt.src[s], si, isf));
}

struct FTab { const void* src[14]; int start[15]; };
__global__ void k_cvt_all(FTab ft, float* __restrict__ dst, const int* __restrict__ fl){
  int isf = fl[0];
  int i = blockIdx.x*256 + threadIdx.x;
  if (i >= ft.start[14]) return;
  int s = 0;
  while (i >= ft.start[s+1]) s++;
  dst[i] = rd(ft.src[s], i - ft.start[s], isf);
}

__global__ void k_build_g(float* __restrict__ g){
  int d = blockIdx.x*256 + threadIdx.x;
  if (d >= SS) return;
  float s = 1.f;
  for (int k = 1; k < 102; ++k){
    int r = (k*d) & (SS-1);
    s += 2.f * cosf(6.28318530718f * (float)r * (1.f/SS));
  }
  g[d] = s * (1.f/SS);
}
__global__ void k_build_cmat(const float* __restrict__ g, US* __restrict__ cm){
  int i = blockIdx.x*256 + threadIdx.x;
  if (i >= SS*SS) return;
  int t = i >> 10, s = i & (SS-1);
  cm[i] = f2b(g[(s - t) & (SS-1)]);
}
__global__ __launch_bounds__(256) void k_transpose_b(const void* __restrict__ x, US* __restrict__ xt, const int* __restrict__ fl){
  int isf = fl[0];
  __shared__ float tl[32][33];
  int b = blockIdx.z, s0 = blockIdx.x*32, d0 = blockIdx.y*32;
  int tx = threadIdx.x & 31, ty = threadIdx.x >> 5;
  for (int i = ty; i < 32; i += 8)
    tl[i][tx] = rd(x, ((long)(b*SS + s0+i))*DD + d0+tx, isf);
  __syncthreads();
  for (int i = ty; i < 32; i += 8)
    xt[((long)(b*DD + d0+i))*SS + s0+tx] = f2b(tl[tx][i]);
}

// ---------------- 8-phase 256x256 MFMA GEMM (K-slice ring, counted vmcnt) ----------------
// Ring layout: A slot s at US offset s*8192 (16 KiB each), B slot s at 32768 + s*8192.
template<int EPI, bool TAPPED>
__global__ __launch_bounds__(512, 2) void k_mfma8(
    const US* __restrict__ A, const US* __restrict__ Bact, void* __restrict__ Out,
    int NYB, int K, long sBbytes, int ldbB, int dil,
    long sOut, int ldo, const float* __restrict__ bias)
{
  __shared__ US ring[65536];   // 128 KiB
  const int bx = blockIdx.x;
  const int ny = bx % NYB, b = bx / NYB;
  const int m0 = blockIdx.y*256, n0 = ny*256;
  const int dd = (TAPPED && dil < 0) ? (1 << (m0 >> 9)) : dil;
  const char* Bb = (const char*)Bact + (long)b*sBbytes;
  const int tid = threadIdx.x;
  const int lane = tid & 63, w = tid >> 6;
  const int wm = w >> 2, wn = w & 3;
  const int col = lane & 15, g = lane >> 4;
  const int NTs = K >> 5;

  int offA[8], offB[4];
  #pragma unroll
  for (int fm = 0; fm < 8; fm++){
    int r = wm*128 + fm*16 + col;
    int R = r >> 1;
    int wg = ((r & 1) << 2) | g;
    offA[fm] = R*128 + ((wg ^ (R & 7)) << 4);
  }
  #pragma unroll
  for (int fn = 0; fn < 4; fn++){
    int r = wn*64 + fn*16 + col;
    int R = r >> 1;
    int wg = ((r & 1) << 2) | g;
    offB[fn] = R*128 + ((wg ^ (R & 7)) << 4);
  }
  int rl[2], gg[2];
  #pragma unroll
  for (int j = 0; j < 2; j++){
    int c = (w*2 + j)*64 + lane;
    int R = c >> 3, f = c & 7;
    int wg = f ^ (R & 7);
    rl[j] = 2*R + (wg >> 2);
    gg[j] = wg & 3;
  }

  auto stageA = [&](int t){
    int slot = t & 3, kb = t << 5;
    #pragma unroll
    for (int j = 0; j < 2; j++){
      const char* ga = (const char*)A + ((long)(m0 + rl[j])*K + kb + gg[j]*8)*2;
      __builtin_amdgcn_global_load_lds((gv1*)ga, (lv3*)&ring[slot*8192 + (w*2 + j)*512], 16, 0, 0);
    }
  };
  auto stageB = [&](int t){
    int slot = t & 3, kb = t << 5;
    int c0 = TAPPED ? (kb & 511) : kb;
    int tapoff = TAPPED ? (((kb >> 9) - 1)*dd) : 0;
    #pragma unroll
    for (int j = 0; j < 2; j++){
      int brow = n0 + rl[j] + tapoff;
      if (TAPPED) brow = brow < 0 ? 0 : (brow > SS-1 ? SS-1 : brow);
      const char* gb = Bb + (long)brow*ldbB + (c0 + gg[j]*8)*2;
      __builtin_amdgcn_global_load_lds((gv1*)gb, (lv3*)&ring[32768 + slot*8192 + (w*2 + j)*512], 16, 0, 0);
    }
  };

  f32x4 acc[8][4];
  #pragma unroll
  for (int i = 0; i < 8; i++)
    #pragma unroll
    for (int j = 0; j < 4; j++) acc[i][j] = (f32x4){0.f,0.f,0.f,0.f};

  stageA(0); stageB(0);
  if (NTs > 1){ stageA(1); stageB(1); }
  if (NTs > 2) stageA(2);
  asm volatile("s_waitcnt vmcnt(6)" ::: "memory");
  __builtin_amdgcn_s_barrier();

  bf16x8 af[4], bf[4];
  for (int ks = 0; ks < NTs; ++ks){
    const char* As = (const char*)&ring[(ks & 3)*8192];
    const char* Bs = (const char*)&ring[32768 + (ks & 3)*8192];
    // phase 0 (m-half 0)
    #pragma unroll
    for (int fn = 0; fn < 4; fn++) bf[fn] = *(const bf16x8*)(Bs + offB[fn]);
    #pragma unroll
    for (int fm = 0; fm < 4; fm++) af[fm] = *(const bf16x8*)(As + offA[fm]);
    if (ks + 2 < NTs) stageB(ks + 2);
    __builtin_amdgcn_s_barrier();
    __builtin_amdgcn_s_setprio(1);
    #pragma unroll
    for (int fm = 0; fm < 4; fm++)
      #pragma unroll
      for (int fn = 0; fn < 4; fn++)
        acc[fm][fn] = __builtin_amdgcn_mfma_f32_16x16x32_bf16(af[fm], bf[fn], acc[fm][fn], 0, 0, 0);
    __builtin_amdgcn_s_setprio(0);
    __builtin_amdgcn_s_barrier();
    // phase 1 (m-half 1)
    #pragma unroll
    for (int fm = 0; fm < 4; fm++) af[fm] = *(const bf16x8*)(As + offA[4 + fm]);
    if (ks + 3 < NTs) stageA(ks + 3);
    __builtin_amdgcn_s_barrier();
    __builtin_amdgcn_s_setprio(1);
    #pragma unroll
    for (int fm = 0; fm < 4; fm++)
      #pragma unroll
      for (int fn = 0; fn < 4; fn++)
        acc[4 + fm][fn] = __builtin_amdgcn_mfma_f32_16x16x32_bf16(af[fm], bf[fn], acc[4 + fm][fn], 0, 0, 0);
    __builtin_amdgcn_s_setprio(0);
    if (ks < NTs - 3)       asm volatile("s_waitcnt vmcnt(6)" ::: "memory");
    else if (ks == NTs - 3) asm volatile("s_waitcnt vmcnt(4)" ::: "memory");
    else if (ks == NTs - 2) asm volatile("s_waitcnt vmcnt(0)" ::: "memory");
    __builtin_amdgcn_s_barrier();
  }

  // ---- epilogue: acc -> swizzled 128 KiB LDS tile -> coalesced stores ----
  US* tile = ring;
  #pragma unroll
  for (int fm = 0; fm < 8; fm++){
    int m_l = wm*128 + fm*16 + g*4;
    float4 bb = *(const float4*)&bias[m0 + m_l];
    const float* bp = (const float*)&bb;
    #pragma unroll
    for (int fn = 0; fn < 4; fn++){
      int n_l = wn*64 + fn*16 + col;
      f32x4 v = acc[fm][fn];
      US pk[4];
      #pragma unroll
      for (int r = 0; r < 4; r++){
        float val = v[r] + bp[r];
        if (EPI == 1) val = 0.5f*val*(1.f + erff(val*0.70710678f));
        pk[r] = f2b(val);
      }
      long byte = (long)n_l*512 + ((((m_l >> 3) ^ (n_l & 7)) << 4) | ((m_l & 7)*2));
      *(int2*)((char*)tile + byte) = *(int2*)pk;
    }
  }
  __syncthreads();          // drain lgkm before cross-wave tile reads
  #pragma unroll
  for (int p = 0; p < 16; p++){
    int chunk = p*512 + tid;
    int rr = chunk >> 5, cg = chunk & 31;
    int4 vv = *(const int4*)((const char*)tile + (long)rr*512 + ((cg ^ (rr & 7)) << 4));
    *(int4*)((US*)Out + (long)b*sOut + (long)(n0 + rr)*ldo + m0 + cg*8) = vv;
  }
}

// ---------------- 128x128 MFMA GEMM ----------------
// EPI: 0=bias store out[b][n][m]; 2=+bn+silu; 3=+silu; 4=wavelet-fused;
//      5=NT store out[b][m][n]; 6=bias store + aux1=x-val + aux2=silu(val).
template<int EPI, bool TAPPED>
__global__ __launch_bounds__(256) void k_mfma(
    const US* __restrict__ A, const US* __restrict__ Bact, void* __restrict__ Out,
    int NYB, int K, long sBbytes, int ldbB, int dil,
    long sOut, int ldo,
    const float* __restrict__ bias, const float* __restrict__ s1v, const float* __restrict__ s2v,
    const float* __restrict__ psiP, const void* __restrict__ xres,
    US* __restrict__ aux1, US* __restrict__ aux2, const int* __restrict__ fl)
{
  __shared__ alignas(16) US shb[2*128*64];
  __shared__ float psh[(EPI==4) ? 512 : 4];
  US* As = shb;
  US* Bs = shb + 128*64;
  const int bx = blockIdx.x;
  const int ny = bx % NYB;
  const int b  = bx / NYB;
  const int m00 = blockIdx.y*128, n0 = ny*128;
  const int dd = (TAPPED && dil < 0) ? (1 << (m00 >> 9)) : dil;
  const char* Bb = (const char*)Bact + (long)b*sBbytes;
  const int tid = threadIdx.x;
  const int lane = tid & 63, w = tid >> 6;
  const int wr = w >> 1, wc = w & 1;
  const int col = lane & 15, g = lane >> 4;

  if (EPI == 4){
    for (int i = tid; i < 512; i += 256)
      psh[i] = psiP[(long)b*4096 + (i >> 7)*SS + n0 + (i & 127)];
  }

  f32x4 acc[4][4];
  f32x4 facc[4][4];
  if (EPI == 4){
    #pragma unroll
    for (int i = 0; i < 4; i++)
      #pragma unroll
      for (int j = 0; j < 4; j++) facc[i][j] = (f32x4){0.f,0.f,0.f,0.f};
  }

  int rows_[4], sls_[4];
  #pragma unroll
  for (int i = 0; i < 4; i++){
    int c = w*256 + i*64 + lane;
    rows_[i] = c >> 3;
    sls_[i] = (c & 7) ^ ((c >> 3) & 7);
  }

  const int NKC = (EPI == 4) ? 4 : 1;
  for (int kc = 0; kc < NKC; ++kc){
    #pragma unroll
    for (int i = 0; i < 4; i++)
      #pragma unroll
      for (int j = 0; j < 4; j++) acc[i][j] = (f32x4){0.f,0.f,0.f,0.f};

    for (int k0 = 0; k0 < K; k0 += 64){
      const int c0 = TAPPED ? (k0 & 511) : k0;
      const int tapoff = TAPPED ? (((k0 >> 9) - 1)*dd) : 0;
      __syncthreads();
      #pragma unroll
      for (int i = 0; i < 4; i++){
        const long arow = (long)(m00 + rows_[i]) + (EPI==4 ? kc*512 : 0);
        const char* ga = (const char*)A + (arow*K + k0)*2 + sls_[i]*16;
        __builtin_amdgcn_global_load_lds((gv1*)ga, (lv3*)&As[(w*256 + i*64)*8], 16, 0, 0);
        int brow = n0 + rows_[i] + tapoff;
        if (TAPPED) brow = brow < 0 ? 0 : (brow > SS-1 ? SS-1 : brow);
        const char* gb = Bb + (long)brow*ldbB + c0*2 + sls_[i]*16;
        __builtin_amdgcn_global_load_lds((gv1*)gb, (lv3*)&Bs[(w*256 + i*64)*8], 16, 0, 0);
      }
      __syncthreads();
      #pragma unroll
      for (int kk = 0; kk < 2; kk++){
        bf16x8 af[4], bf[4];
        #pragma unroll
        for (int f = 0; f < 4; f++){
          int rowa = wr*64 + f*16 + col;
          int sla = (g + kk*4) ^ (rowa & 7);
          af[f] = *(const bf16x8*)&As[rowa*64 + sla*8];
          int rowb = wc*64 + f*16 + col;
          int slb = (g + kk*4) ^ (rowb & 7);
          bf[f] = *(const bf16x8*)&Bs[rowb*64 + slb*8];
        }
        #pragma unroll
        for (int fm = 0; fm < 4; fm++)
          #pragma unroll
          for (int fn = 0; fn < 4; fn++)
            acc[fm][fn] = __builtin_amdgcn_mfma_f32_16x16x32_bf16(af[fm], bf[fn], acc[fm][fn], 0, 0, 0);
      }
    }

    if (EPI == 4){
      #pragma unroll
      for (int fm = 0; fm < 4; fm++){
        const int mm_l = wr*64 + fm*16 + g*4;
        float bb[4];
        #pragma unroll
        for (int r = 0; r < 4; r++) bb[r] = bias[kc*512 + m00 + mm_l + r];
        #pragma unroll
        for (int fn = 0; fn < 4; fn++){
          float p = psh[kc*128 + wc*64 + fn*16 + col];
          #pragma unroll
          for (int r = 0; r < 4; r++)
            facc[fm][fn][r] += p * (acc[fm][fn][r] + bb[r]);
        }
      }
    }
  }

  __syncthreads();
  US* tile = shb;
  #pragma unroll
  for (int fm = 0; fm < 4; fm++){
    const int mm_l = wr*64 + fm*16 + g*4;
    float bb[4];
    if (EPI == 0 || EPI == 2 || EPI == 3 || EPI == 6){
      #pragma unroll
      for (int r = 0; r < 4; r++) bb[r] = bias[m00 + mm_l + r];
    }
    #pragma unroll
    for (int fn = 0; fn < 4; fn++){
      const int nn_l = wc*64 + fn*16 + col;
      f32x4 v = (EPI == 4) ? facc[fm][fn] : acc[fm][fn];
      if (EPI == 5){
        #pragma unroll
        for (int r = 0; r < 4; r++){
          int row = mm_l + r;
          int byte = row*256 + ((nn_l*2) ^ ((row & 7) << 4));
          *(US*)((char*)tile + byte) = f2b(v[r]);
        }
      } else {
        US pk[4];
        #pragma unroll
        for (int r = 0; r < 4; r++){
          float val = v[r];
          if (EPI != 4) val += bb[r];
          if (EPI == 2){ int m = m00 + mm_l + r; val = val*(s1v[m]*0.99999500f) + s2v[m]; val = val/(1.f + expf(-val)); }
          if (EPI == 3){ val = val/(1.f + expf(-val)); }
          pk[r] = f2b(val);
        }
        int byte = nn_l*256 + ((mm_l*2) ^ ((nn_l & 7) << 4));
        *(int2*)((char*)tile + byte) = *(int2*)pk;
      }
    }
  }
  __syncthreads();
  const int r0 = tid >> 4, c = tid & 15;
  const int isf = (EPI == 6) ? fl[0] : 0;
  #pragma unroll
  for (int p = 0; p < 8; p++){
    int r = p*16 + r0;
    int4 vv = *(const int4*)((const char*)tile + r*256 + ((c*16) ^ ((r & 7) << 4)));
    long obase = (EPI == 5) ? ((long)b*sOut + (long)(m00 + r)*ldo + n0)
                            : ((long)b*sOut + (long)(n0 + r)*ldo + m00);
    *(int4*)((US*)Out + obase + c*8) = vv;
    if (EPI == 6){
      long eb = obase + c*8;
      const US* vp = (const US*)&vv;
      US dpk[8], lpk[8];
      #pragma unroll
      for (int q = 0; q < 8; q++){
        float sv = b2sf(vp[q]);
        float xv = rd(xres, eb + q, isf);
        dpk[q] = f2b(xv - sv);
        lpk[q] = f2b(sv/(1.f + expf(-sv)));
      }
      *(int4*)&aux1[eb] = *(int4*)dpk;
      *(int4*)&aux2[eb] = *(int4*)lpk;
    }
  }
}

__global__ __launch_bounds__(256) void k_pool1(const US* __restrict__ h2, float* __restrict__ part){
  int blk = blockIdx.x;
  int b = blk >> 3, ch = blk & 7;
  int c = threadIdx.x;
  float s = 0.f;
  for (int t = ch*128; t < ch*128 + 128; t++) s += b2sf(h2[((long)(b*SS + t))*HD + c]);
  part[(blk << 8) | c] = s;
}
__global__ __launch_bounds__(256) void k_pool2(const float* __restrict__ part, float* __restrict__ feat){
  int b = blockIdx.x, c = threadIdx.x;
  float s = 0.f;
  for (int ch = 0; ch < 8; ch++) s += part[((b*8 + ch) << 8) | c];
  feat[b*HD + c] = s * (1.f/SS);
}
__global__ void k_params(const float* __restrict__ feat, const float* __restrict__ pw,
                         const float* __restrict__ pb, float* __restrict__ dynA, float* __restrict__ dynB){
  int t = threadIdx.x;
  if (t >= 128) return;
  int b = t >> 3, j = t & 7;
  float s = pb[j];
  for (int c = 0; c < HD; c++) s += feat[b*HD + c]*pw[j*HD + c];
  int k = j >> 1;
  if ((j & 1) == 0){
    float sp = s > 20.f ? s : log1pf(expf(s));
    dynA[b*4 + k] = sp + 0.01f;
  } else {
    dynB[b*4 + k] = 1024.f/(1.f + expf(-s));
  }
}
__global__ void k_psi(const float* __restrict__ dynA, const float* __restrict__ dynB, float* __restrict__ psi){
  int i = blockIdx.x*256 + threadIdx.x;
  if (i >= NB*4*SS) return;
  int b = i >> 12, k = (i >> 10) & 3, s = i & (SS-1);
  float u = ((float)s - dynB[b*4 + k]) / dynA[b*4 + k];
  psi[i] = 0.86732507f*(1.f - u*u)*expf(-0.5f*u*u);
}
__global__ __launch_bounds__(128) void k_final(const US* __restrict__ base, const US* __restrict__ kan,
    const US* __restrict__ gate, const void* __restrict__ x,
    void* __restrict__ out, const float* __restrict__ lng, const float* __restrict__ lnb,
    const int* __restrict__ fl){
  int isf = fl[0];
  long row = blockIdx.x;
  int t = threadIdx.x;
  long off = row*DD + t*4;
  ushort4 bs = *(const ushort4*)&base[off];
  ushort4 gt = *(const ushort4*)&gate[off];
  ushort4 kn = *(const ushort4*)&kan[off];
  float xv[4];
  if (isf){ float4 q = *(const float4*)((const float*)x + off); xv[0]=q.x; xv[1]=q.y; xv[2]=q.z; xv[3]=q.w; }
  else { ushort4 q = *(const ushort4*)((const US*)x + off); xv[0]=b2sf(q.x); xv[1]=b2sf(q.y); xv[2]=b2sf(q.z); xv[3]=b2sf(q.w); }
  float bv[4] = {b2sf(bs.x), b2sf(bs.y), b2sf(bs.z), b2sf(bs.w)};
  float gv[4] = {b2sf(gt.x), b2sf(gt.y), b2sf(gt.z), b2sf(gt.w)};
  const US* kp = (const US*)&kn;
  float y[4];
  float sm = 0.f, ssq = 0.f;
  #pragma unroll
  for (int r = 0; r < 4; r++){
    float amp = 2.f/(1.f + expf(-gv[r]));
    y[r] = bv[r] + b2sf(kp[r])*amp + xv[r];
    sm += y[r]; ssq += y[r]*y[r];
  }
  for (int o = 32; o; o >>= 1){ sm += __shfl_down(sm, o); ssq += __shfl_down(ssq, o); }
  __shared__ float sh[4];
  int lane = t & 63, wid = t >> 6;
  if (lane == 0){ sh[wid*2] = sm; sh[wid*2+1] = ssq; }
  __syncthreads();
  float S1 = sh[0] + sh[2], S2 = sh[1] + sh[3];
  float mean = S1*(1.f/DD), var = S2*(1.f/DD) - mean*mean;
  float rstd = rsqrtf(var + 1e-5f);
  #pragma unroll
  for (int r = 0; r < 4; r++){
    int d = t*4 + r;
    float val = (y[r] - mean)*rstd*lng[d] + lnb[d];
    if (isf) ((float*)out)[off + r] = val;
    else     ((US*)out)[off + r] = f2b(val);
  }
}

extern "C" void kernel_launch(void* const* d_in, const int* in_sizes, int n_in,
                              void* d_out, int out_size, void* d_ws, size_t ws_size,
                              hipStream_t stream){
  const void* x       = d_in[0];
  const void* conv_w  = d_in[1];
  const void* conv_b  = d_in[2];
  const void* fusion_w= d_in[3];
  const void* fusion_b= d_in[4];
  const void* refine_w= d_in[5];
  const void* refine_b= d_in[6];
  const void* hyp1_w  = d_in[7];
  const void* hyp1_b  = d_in[8];
  const void* bn_g    = d_in[9];
  const void* bn_b    = d_in[10];
  const void* hyp2_w  = d_in[11];
  const void* hyp2_b  = d_in[12];
  const void* proj_w  = d_in[13];
  const void* proj_b  = d_in[14];
  const void* gate_w  = d_in[15];
  const void* gate_b  = d_in[16];
  const void* base_w  = d_in[17];
  const void* base_b  = d_in[18];
  const void* wav_w   = d_in[19];
  const void* wav_b   = d_in[20];
  const void* ln_g    = d_in[21];
  const void* ln_b    = d_in[22];

  char* wsb = (char*)d_ws;
  long off = 0;
  auto AA = [&](long bytes)->char*{ char* p = wsb + off; off += (bytes + 255) & ~255L; return p; };
  US* smA   = (US*)AA((long)NB*SS*DD*2);
  US* smB   = (US*)AA((long)NB*SS*DD*2);
  US* xTh   = (US*)AA((long)NB*SS*DD*2);
  US* cc    = (US*)AA((long)NB*SS*2048*2);
  US* baseB = (US*)AA((long)NB*SS*DD*2);
  US* WBLK  = (US*)AA(7733248L*2);
  US* Cm    = (US*)AA(1024L*1024*2);
  float* gvec = (float*)AA(1024*4);
  float* FBLK = (float*)AA(11016L*4);
  float* feat = (float*)AA(16*256*4);
  float* part = (float*)AA(16*8*256*4);
  float* dynA = (float*)AA(64*4);
  float* dynB = (float*)AA(64*4);
  float* psi  = (float*)AA((long)NB*4*SS*4);
  int* flag   = (int*)AA(64);
  if ((size_t)off > ws_size) return;

  US* Wc  = WBLK;
  US* Wr  = Wc  + 3145728L;
  US* Wh1 = Wr  + 786432L;
  US* Wh2 = Wh1 + 786432L;
  US* Wwv = Wh2 + 393216L;
  US* Fw  = Wwv + 1048576L;
  US* BW  = Fw  + 1048576L;
  US* GW  = BW  + 262144L;
  float* cb_f = FBLK;
  float* fz_b = cb_f + 2048;
  float* rf_b = fz_b + 512;
  float* h1_b = rf_b + 512;
  float* h2_b = h1_b + 512;
  float* bs_b = h2_b + 256;
  float* gt_b = bs_b + 512;
  float* wv_b = gt_b + 512;
  float* bngf = wv_b + 2048;
  float* bnbf = bngf + 512;
  float* pwf  = bnbf + 512;
  float* pbf  = pwf  + 2048;
  float* lngf = pbf  + 8;
  float* lnbf = lngf + 512;
  US* spike = cc;
  US* baseO = cc + 8388608L;
  US* kanb  = cc + 16777216L;
  US* h2b   = cc + 25165824L;

  auto g1 = [](long n){ return dim3((unsigned)((n + 255)/256)); };
  const long sAct = (long)SS*DD*2;
  const long sCC  = (long)SS*2048*2;
  const long oAct = (long)SS*DD;
  const long oCC  = (long)SS*2048;
  const long oH2  = (long)SS*HD;

  k_detect<<<1, 256, 0, stream>>>(x, flag);

  { WTab wt;
    const void* srcs[8] = {conv_w, refine_w, hyp1_w, hyp2_w, wav_w, fusion_w, base_w, gate_w};
    long sizes[8] = {3145728, 786432, 786432, 393216, 1048576, 1048576, 262144, 262144};
    int types[8] = {0,0,0,0,1,2,2,2};
    int Cs[8]    = {512,512,512,512,0,0,0,0};
    long acc_ = 0;
    for (int i = 0; i < 8; i++){ wt.src[i]=srcs[i]; wt.start[i]=acc_; wt.type[i]=types[i]; wt.C[i]=Cs[i]; acc_ += sizes[i]; }
    wt.start[8] = acc_;
    k_prep_w<<<g1(acc_), 256, 0, stream>>>(wt, WBLK, flag);
  }
  { FTab ft;
    const void* srcs[14] = {conv_b, fusion_b, refine_b, hyp1_b, hyp2_b, base_b, gate_b,
                            wav_b, bn_g, bn_b, proj_w, proj_b, ln_g, ln_b};
    int sizes[14] = {2048,512,512,512,256,512,512,2048,512,512,2048,8,512,512};
    int acc_ = 0;
    for (int i = 0; i < 14; i++){ ft.src[i]=srcs[i]; ft.start[i]=acc_; acc_ += sizes[i]; }
    ft.start[14] = acc_;
    k_cvt_all<<<g1(acc_), 256, 0, stream>>>(ft, FBLK, flag);
  }
  k_build_g<<<g1(SS), 256, 0, stream>>>(gvec);
  k_build_cmat<<<g1((long)SS*SS), 256, 0, stream>>>(gvec, Cm);
  k_transpose_b<<<dim3(SS/32, DD/32, NB), 256, 0, stream>>>(x, xTh, flag);

  // circulant low-pass
  k_mfma<5,false><<<dim3(4*NB, 8), 256, 0, stream>>>(Cm, xTh, smA,
      4, 1024, (long)DD*SS*2, SS*2, 0, oAct, DD,
      nullptr, nullptr, nullptr, nullptr, nullptr, nullptr, nullptr, nullptr);

  // it 0: 8-phase merged conv -> fusion
  k_mfma8<1,true><<<dim3(4*NB, 8), 512, 0, stream>>>(Wc, smA, cc,
      4, 1536, sAct, DD*2, -1, oCC, 2048, cb_f);
  k_mfma<0,false><<<dim3(8*NB, 4), 256, 0, stream>>>(Fw, cc, smB,
      8, 2048, sCC, 4096, 0, oAct, DD,
      fz_b, nullptr, nullptr, nullptr, nullptr, nullptr, nullptr, nullptr);
  // it 1: conv -> fusion (+fused diff & silu)
  k_mfma8<1,true><<<dim3(4*NB, 8), 512, 0, stream>>>(Wc, smB, cc,
      4, 1536, sAct, DD*2, -1, oCC, 2048, cb_f);
  k_mfma<6,false><<<dim3(8*NB, 4), 256, 0, stream>>>(Fw, cc, smA,
      8, 2048, sCC, 4096, 0, oAct, DD,
      fz_b, nullptr, nullptr, nullptr, x, smB, baseB, flag);

  // spike = refine(diff)
  k_mfma<0,true><<<dim3(8*NB, 4), 256, 0, stream>>>(Wr, smB, spike,
      8, 1536, sAct, DD*2, 1, oAct, DD,
      rf_b, nullptr, nullptr, nullptr, nullptr, nullptr, nullptr, nullptr);

  // hypernet
  k_mfma<2,true><<<dim3(8*NB, 4), 256, 0, stream>>>(Wh1, smA, xTh,
      8, 1536, sAct, DD*2, 1, oAct, DD,
      h1_b, bngf, bnbf, nullptr, nullptr, nullptr, nullptr, nullptr);
  k_mfma<3,true><<<dim3(8*NB, 2), 256, 0, stream>>>(Wh2, xTh, h2b,
      8, 1536, sAct, DD*2, 1, oH2, HD,
      h2_b, nullptr, nullptr, nullptr, nullptr, nullptr, nullptr, nullptr);
  k_pool1<<<NB*8, 256, 0, stream>>>(h2b, part);
  k_pool2<<<NB, 256, 0, stream>>>(part, feat);
  k_params<<<1, 128, 0, stream>>>(feat, pwf, pbf, dynA, dynB);
  k_psi<<<g1(NB*4*SS), 256, 0, stream>>>(dynA, dynB, psi);

  // base / gate
  k_mfma<0,false><<<dim3(8*NB, 4), 256, 0, stream>>>(BW, baseB, baseO,
      8, 512, sAct, DD*2, 0, oAct, DD,
      bs_b, nullptr, nullptr, nullptr, nullptr, nullptr, nullptr, nullptr);
  k_mfma<0,false><<<dim3(8*NB, 4), 256, 0, stream>>>(GW, baseO, xTh,
      8, 512, sAct, DD*2, 0, oAct, DD,
      gt_b, nullptr, nullptr, nullptr, nullptr, nullptr, nullptr, nullptr);

  // psi-fused wavelet
  k_mfma<4,false><<<dim3(8*NB, 4), 256, 0, stream>>>(Wwv, spike, kanb,
      8, 512, sAct, DD*2, 0, oAct, DD,
      wv_b, nullptr, nullptr, psi, nullptr, nullptr, nullptr, nullptr);

  // combine + residual + LayerNorm
  k_final<<<NB*SS, 128, 0, stream>>>(baseO, kanb, xTh, x, d_out, lngf, lnbf, flag);
}